// Round 1
// baseline (406.425 us; speedup 1.0000x reference)
//
#include <hip/hip_runtime.h>
#include <hip/hip_bf16.h>

#define SVOX 13824   // 24*24*24
#define CIN 128
#define NHEAD 4
#define HDIM 32

// ---------------------------------------------------------------------------
// Kernel 1: QKV projection GEMM.
//   X   [B][128][S]  (c-major, spatial contiguous)
//   W   [384][128]
//   out [B][3][4][S][32]  (voxel-major, hd contiguous -> float4 loads in attn)
// Block tile: 64 o x 64 s, K=128 in two 64-chunks. 256 thr, 4x4 microtile.
// ---------------------------------------------------------------------------
__global__ __launch_bounds__(256) void qkv_gemm_kernel(
    const float* __restrict__ X,
    const float* __restrict__ W,
    const float* __restrict__ bias,
    float* __restrict__ out)
{
    __shared__ float smem[128*64 + 64*68];   // Xs[128][64] + Ws[64][68]
    float* Xs = smem;
    float* Ws = smem + 128*64;

    int t  = threadIdx.x;
    int s0 = blockIdx.x * 64;
    int o0 = blockIdx.y * 64;
    int b  = blockIdx.z;

    const float* Xg = X + (size_t)b*CIN*SVOX + s0;
    #pragma unroll
    for (int k2 = 0; k2 < 8; k2++) {
        int idx = t + k2*256;
        int c = idx >> 4, sv4 = idx & 15;
        *(float4*)(&Xs[c*64 + sv4*4]) = *(const float4*)(Xg + (size_t)c*SVOX + sv4*4);
    }

    int tx = t & 15, ty = t >> 4;
    float acc[4][4] = {{0.f,0.f,0.f,0.f},{0.f,0.f,0.f,0.f},{0.f,0.f,0.f,0.f},{0.f,0.f,0.f,0.f}};

    for (int kk = 0; kk < 2; kk++) {
        __syncthreads();
        #pragma unroll
        for (int k2 = 0; k2 < 4; k2++) {
            int idx = t + k2*256;
            int o = idx >> 4, cv4 = idx & 15;
            *(float4*)(&Ws[o*68 + cv4*4]) =
                *(const float4*)(W + (size_t)(o0+o)*CIN + kk*64 + cv4*4);
        }
        __syncthreads();
        #pragma unroll
        for (int c4 = 0; c4 < 16; c4++) {
            float4 wq[4];
            #pragma unroll
            for (int i = 0; i < 4; i++)
                wq[i] = *(const float4*)(&Ws[(ty*4+i)*68 + c4*4]);
            int cb = kk*64 + c4*4;
            float4 xq[4];
            #pragma unroll
            for (int r = 0; r < 4; r++)
                xq[r] = *(const float4*)(&Xs[(cb+r)*64 + tx*4]);
            const float* wf = (const float*)wq;
            const float* xf = (const float*)xq;
            #pragma unroll
            for (int i = 0; i < 4; i++)
                #pragma unroll
                for (int cc = 0; cc < 4; cc++)
                    #pragma unroll
                    for (int j = 0; j < 4; j++)
                        acc[i][j] += wf[i*4+cc] * xf[cc*4+j];
        }
    }

    // Epilogue: add bias, transpose via LDS, store to [B][3][4][S][32]
    __syncthreads();
    float* T = smem;   // [64][65]
    float bv[4];
    #pragma unroll
    for (int i = 0; i < 4; i++) bv[i] = bias[o0 + ty*4 + i];
    #pragma unroll
    for (int i = 0; i < 4; i++)
        #pragma unroll
        for (int j = 0; j < 4; j++)
            T[(ty*4+i)*65 + tx*4+j] = acc[i][j] + bv[i];
    __syncthreads();

    int og  = t & 15;        // group of 4 output channels
    int sl0 = t >> 4;        // s-local base, +16 per iter
    int o_g = o0 + og*4;
    int part = o_g >> 7;
    int n    = (o_g >> 5) & 3;
    int ic   = o_g & 31;
    float* dst0 = out + ((((size_t)b*3 + part)*NHEAD + n)*SVOX)*HDIM + ic;
    #pragma unroll
    for (int r = 0; r < 4; r++) {
        int sl = sl0 + r*16;
        float4 v;
        v.x = T[(og*4+0)*65 + sl];
        v.y = T[(og*4+1)*65 + sl];
        v.z = T[(og*4+2)*65 + sl];
        v.w = T[(og*4+3)*65 + sl];
        *(float4*)(dst0 + (size_t)(s0+sl)*HDIM) = v;
    }
}

// ---------------------------------------------------------------------------
// Kernel 2: windowed 3x3x3 attention. One thread per (b, head, voxel).
//   qkv [B][3][4][S][32], pos [32][27], aout [B][128][S]
// OOB window slots: score = q.pos_embed (k_pad=0), v contribution = 0.
// ---------------------------------------------------------------------------
__global__ __launch_bounds__(256) void attn_kernel(
    const float* __restrict__ qkv,
    const float* __restrict__ pos,
    float* __restrict__ aout)
{
    __shared__ float pe[32*28];
    int t = threadIdx.x;
    for (int i = t; i < 32*28; i += 256) {
        int r = i / 28, c = i - r*28;
        pe[i] = (c < 27) ? pos[r*27 + c] : 0.f;
    }
    __syncthreads();

    int sv = blockIdx.x * 256 + t;
    int n  = blockIdx.y;
    int b  = blockIdx.z;

    const float* qb = qkv + (((size_t)b*3 + 0)*NHEAD + n)*(size_t)SVOX*HDIM;
    const float* kb = qkv + (((size_t)b*3 + 1)*NHEAD + n)*(size_t)SVOX*HDIM;
    const float* vb = qkv + (((size_t)b*3 + 2)*NHEAD + n)*(size_t)SVOX*HDIM;

    float q[32];
    #pragma unroll
    for (int g = 0; g < 8; g++) {
        float4 v = *(const float4*)(qb + (size_t)sv*HDIM + g*4);
        q[g*4+0]=v.x; q[g*4+1]=v.y; q[g*4+2]=v.z; q[g*4+3]=v.w;
    }

    // qpe[w] = sum_ic q[ic]*pe[ic][w]  (vectorized over window slots)
    float sc[28];
    #pragma unroll
    for (int g = 0; g < 7; g++) {
        float ax=0.f, ay=0.f, az=0.f, aw=0.f;
        #pragma unroll
        for (int icc = 0; icc < 32; icc++) {
            float4 p = *(const float4*)(&pe[icc*28 + g*4]);
            ax += q[icc]*p.x; ay += q[icc]*p.y; az += q[icc]*p.z; aw += q[icc]*p.w;
        }
        sc[g*4+0]=ax; sc[g*4+1]=ay; sc[g*4+2]=az; sc[g*4+3]=aw;
    }

    int d = sv / 576; int rem = sv - d*576; int h = rem / 24; int w = rem - h*24;
    const float scale = 0.17677669529663687f;   // 32^-0.5

    float mx = -1e30f;
    int widx = 0;
    #pragma unroll
    for (int di = -1; di <= 1; di++)
    #pragma unroll
    for (int dj = -1; dj <= 1; dj++)
    #pragma unroll
    for (int dl = -1; dl <= 1; dl++) {
        float s = sc[widx];
        int dd = d+di, hh = h+dj, ww = w+dl;
        if (((unsigned)dd < 24u) & ((unsigned)hh < 24u) & ((unsigned)ww < 24u)) {
            const float* kp = kb + (size_t)(sv + di*576 + dj*24 + dl)*HDIM;
            float a = 0.f;
            #pragma unroll
            for (int g = 0; g < 8; g++) {
                float4 kv = *(const float4*)(kp + g*4);
                a += q[g*4+0]*kv.x + q[g*4+1]*kv.y + q[g*4+2]*kv.z + q[g*4+3]*kv.w;
            }
            s += a;
        }
        s *= scale;
        sc[widx] = s;
        mx = fmaxf(mx, s);
        widx++;
    }

    float sum = 0.f;
    #pragma unroll
    for (int w2 = 0; w2 < 27; w2++) {
        float e = __expf(sc[w2] - mx);
        sc[w2] = e;
        sum += e;
    }
    float inv = 1.f / sum;

    float o[32];
    #pragma unroll
    for (int icc = 0; icc < 32; icc++) o[icc] = 0.f;

    widx = 0;
    #pragma unroll
    for (int di = -1; di <= 1; di++)
    #pragma unroll
    for (int dj = -1; dj <= 1; dj++)
    #pragma unroll
    for (int dl = -1; dl <= 1; dl++) {
        int dd = d+di, hh = h+dj, ww = w+dl;
        if (((unsigned)dd < 24u) & ((unsigned)hh < 24u) & ((unsigned)ww < 24u)) {
            float p = sc[widx];
            const float* vp = vb + (size_t)(sv + di*576 + dj*24 + dl)*HDIM;
            #pragma unroll
            for (int g = 0; g < 8; g++) {
                float4 vv = *(const float4*)(vp + g*4);
                o[g*4+0] += p*vv.x; o[g*4+1] += p*vv.y;
                o[g*4+2] += p*vv.z; o[g*4+3] += p*vv.w;
            }
        }
        widx++;
    }

    float* op = aout + ((size_t)b*CIN + n*HDIM)*SVOX + sv;
    #pragma unroll
    for (int icc = 0; icc < 32; icc++)
        op[(size_t)icc*SVOX] = o[icc] * inv;
}

// ---------------------------------------------------------------------------
// Kernel 3: output projection GEMM.
//   Xa [B][128][S], W [128][128], out [B][128][S]
// ---------------------------------------------------------------------------
__global__ __launch_bounds__(256) void proj_gemm_kernel(
    const float* __restrict__ X,
    const float* __restrict__ W,
    const float* __restrict__ bias,
    float* __restrict__ out)
{
    __shared__ float smem[128*64 + 64*68];
    float* Xs = smem;
    float* Ws = smem + 128*64;

    int t  = threadIdx.x;
    int s0 = blockIdx.x * 64;
    int o0 = blockIdx.y * 64;
    int b  = blockIdx.z;

    const float* Xg = X + (size_t)b*CIN*SVOX + s0;
    #pragma unroll
    for (int k2 = 0; k2 < 8; k2++) {
        int idx = t + k2*256;
        int c = idx >> 4, sv4 = idx & 15;
        *(float4*)(&Xs[c*64 + sv4*4]) = *(const float4*)(Xg + (size_t)c*SVOX + sv4*4);
    }

    int tx = t & 15, ty = t >> 4;
    float acc[4][4] = {{0.f,0.f,0.f,0.f},{0.f,0.f,0.f,0.f},{0.f,0.f,0.f,0.f},{0.f,0.f,0.f,0.f}};

    for (int kk = 0; kk < 2; kk++) {
        __syncthreads();
        #pragma unroll
        for (int k2 = 0; k2 < 4; k2++) {
            int idx = t + k2*256;
            int o = idx >> 4, cv4 = idx & 15;
            *(float4*)(&Ws[o*68 + cv4*4]) =
                *(const float4*)(W + (size_t)(o0+o)*CIN + kk*64 + cv4*4);
        }
        __syncthreads();
        #pragma unroll
        for (int c4 = 0; c4 < 16; c4++) {
            float4 wq[4];
            #pragma unroll
            for (int i = 0; i < 4; i++)
                wq[i] = *(const float4*)(&Ws[(ty*4+i)*68 + c4*4]);
            int cb = kk*64 + c4*4;
            float4 xq[4];
            #pragma unroll
            for (int r = 0; r < 4; r++)
                xq[r] = *(const float4*)(&Xs[(cb+r)*64 + tx*4]);
            const float* wf = (const float*)wq;
            const float* xf = (const float*)xq;
            #pragma unroll
            for (int i = 0; i < 4; i++)
                #pragma unroll
                for (int cc = 0; cc < 4; cc++)
                    #pragma unroll
                    for (int j = 0; j < 4; j++)
                        acc[i][j] += wf[i*4+cc] * xf[cc*4+j];
        }
    }

    float* dstB = out + ((size_t)b*CIN + o0 + ty*4)*SVOX + s0 + tx*4;
    #pragma unroll
    for (int i = 0; i < 4; i++) {
        float bi = bias[o0 + ty*4 + i];
        float4 v;
        v.x = acc[i][0] + bi; v.y = acc[i][1] + bi;
        v.z = acc[i][2] + bi; v.w = acc[i][3] + bi;
        *(float4*)(dstB + (size_t)i*SVOX) = v;
    }
}

extern "C" void kernel_launch(void* const* d_in, const int* in_sizes, int n_in,
                              void* d_out, int out_size, void* d_ws, size_t ws_size,
                              hipStream_t stream) {
    const float* x      = (const float*)d_in[0];
    const float* qkv_w  = (const float*)d_in[1];
    const float* qkv_b  = (const float*)d_in[2];
    const float* proj_w = (const float*)d_in[3];
    const float* proj_b = (const float*)d_in[4];
    const float* pos    = (const float*)d_in[5];
    float* out = (float*)d_out;

    float* qkv_t  = (float*)d_ws;                               // [2][3][4][S][32]
    float* attn_o = qkv_t + (size_t)2*3*NHEAD*SVOX*HDIM;        // [2][128][S]

    qkv_gemm_kernel<<<dim3(SVOX/64, 384/64, 2), 256, 0, stream>>>(x, qkv_w, qkv_b, qkv_t);
    attn_kernel<<<dim3(SVOX/256, NHEAD, 2), 256, 0, stream>>>(qkv_t, pos, attn_o);
    proj_gemm_kernel<<<dim3(SVOX/64, CIN/64, 2), 256, 0, stream>>>(attn_o, proj_w, proj_b, out);
}

// Round 2
// 115.347 us; speedup vs baseline: 3.5235x; 3.5235x over previous
//
#include <hip/hip_runtime.h>
#include <hip/hip_bf16.h>

#define SVOX 13824   // 24*24*24
#define CIN 128
#define NHEAD 4
#define HDIM 32

// ---------------------------------------------------------------------------
// Kernel 1: QKV projection GEMM.
//   X   [B][128][S]  (c-major, spatial contiguous)
//   W   [384][128]
//   out [B][3][4][S][32]  (voxel-major, hd contiguous -> float4 loads in attn)
// ---------------------------------------------------------------------------
__global__ __launch_bounds__(256) void qkv_gemm_kernel(
    const float* __restrict__ X,
    const float* __restrict__ W,
    const float* __restrict__ bias,
    float* __restrict__ out)
{
    __shared__ float smem[128*64 + 64*68];   // Xs[128][64] + Ws[64][68]
    float* Xs = smem;
    float* Ws = smem + 128*64;

    int t  = threadIdx.x;
    int s0 = blockIdx.x * 64;
    int o0 = blockIdx.y * 64;
    int b  = blockIdx.z;

    const float* Xg = X + (size_t)b*CIN*SVOX + s0;
    #pragma unroll
    for (int k2 = 0; k2 < 8; k2++) {
        int idx = t + k2*256;
        int c = idx >> 4, sv4 = idx & 15;
        *(float4*)(&Xs[c*64 + sv4*4]) = *(const float4*)(Xg + (size_t)c*SVOX + sv4*4);
    }

    int tx = t & 15, ty = t >> 4;
    float acc[4][4] = {{0.f,0.f,0.f,0.f},{0.f,0.f,0.f,0.f},{0.f,0.f,0.f,0.f},{0.f,0.f,0.f,0.f}};

    for (int kk = 0; kk < 2; kk++) {
        __syncthreads();
        #pragma unroll
        for (int k2 = 0; k2 < 4; k2++) {
            int idx = t + k2*256;
            int o = idx >> 4, cv4 = idx & 15;
            *(float4*)(&Ws[o*68 + cv4*4]) =
                *(const float4*)(W + (size_t)(o0+o)*CIN + kk*64 + cv4*4);
        }
        __syncthreads();
        #pragma unroll
        for (int c4 = 0; c4 < 16; c4++) {
            float4 wq[4];
            #pragma unroll
            for (int i = 0; i < 4; i++)
                wq[i] = *(const float4*)(&Ws[(ty*4+i)*68 + c4*4]);
            int cb = kk*64 + c4*4;
            float4 xq[4];
            #pragma unroll
            for (int r = 0; r < 4; r++)
                xq[r] = *(const float4*)(&Xs[(cb+r)*64 + tx*4]);
            const float* wf = (const float*)wq;
            const float* xf = (const float*)xq;
            #pragma unroll
            for (int i = 0; i < 4; i++)
                #pragma unroll
                for (int cc = 0; cc < 4; cc++)
                    #pragma unroll
                    for (int j = 0; j < 4; j++)
                        acc[i][j] += wf[i*4+cc] * xf[cc*4+j];
        }
    }

    // Epilogue: add bias, transpose via LDS, store to [B][3][4][S][32]
    __syncthreads();
    float* T = smem;   // [64][65]
    float bv[4];
    #pragma unroll
    for (int i = 0; i < 4; i++) bv[i] = bias[o0 + ty*4 + i];
    #pragma unroll
    for (int i = 0; i < 4; i++)
        #pragma unroll
        for (int j = 0; j < 4; j++)
            T[(ty*4+i)*65 + tx*4+j] = acc[i][j] + bv[i];
    __syncthreads();

    int og  = t & 15;
    int sl0 = t >> 4;
    int o_g = o0 + og*4;
    int part = o_g >> 7;
    int n    = (o_g >> 5) & 3;
    int ic   = o_g & 31;
    float* dst0 = out + ((((size_t)b*3 + part)*NHEAD + n)*SVOX)*HDIM + ic;
    #pragma unroll
    for (int r = 0; r < 4; r++) {
        int sl = sl0 + r*16;
        float4 v;
        v.x = T[(og*4+0)*65 + sl];
        v.y = T[(og*4+1)*65 + sl];
        v.z = T[(og*4+2)*65 + sl];
        v.w = T[(og*4+3)*65 + sl];
        *(float4*)(dst0 + (size_t)(s0+sl)*HDIM) = v;
    }
}

// ---------------------------------------------------------------------------
// Kernel 2: windowed 3x3x3 attention, 4 threads per (voxel, head).
//   qkv [B][3][4][S][32], pos [32][27], aout [B][128][S]
// Each 4-lane group owns one voxel-head; lane handles 8 channels.
// Scores reduced across the group via 2x shfl_xor; softmax redundant.
// OOB window slots: score = q.pos_embed (k_pad=0), v contribution = 0.
// ---------------------------------------------------------------------------
__global__ __launch_bounds__(256) void attn_kernel(
    const float* __restrict__ qkv,
    const float* __restrict__ pos,
    float* __restrict__ aout)
{
    __shared__ float pe_t[27*32];   // pos transposed: [w][c]
    __shared__ float ot[64*33];     // output transpose buffer

    int t = threadIdx.x;
    for (int i = t; i < 27*32; i += 256) {
        int w = i >> 5, c = i & 31;
        pe_t[i] = pos[c*27 + w];
    }
    __syncthreads();

    int vloc = t >> 2;              // 0..63 voxel within block
    int sub  = t & 3;               // channel group (8 ch)
    int s0   = blockIdx.x * 64;
    int sv   = s0 + vloc;
    int n    = blockIdx.y;
    int b    = blockIdx.z;

    const float* qb = qkv + (((size_t)b*3 + 0)*NHEAD + n)*(size_t)SVOX*HDIM;
    const float* kb = qkv + (((size_t)b*3 + 1)*NHEAD + n)*(size_t)SVOX*HDIM;
    const float* vb = qkv + (((size_t)b*3 + 2)*NHEAD + n)*(size_t)SVOX*HDIM;

    const float* qp = qb + (size_t)sv*HDIM + sub*8;
    float4 qa = *(const float4*)(qp);
    float4 qc = *(const float4*)(qp + 4);

    // partial scores: qpe over this lane's 8 channels
    float sc[27];
    #pragma unroll
    for (int w = 0; w < 27; w++) {
        float4 p0 = *(const float4*)(&pe_t[w*32 + sub*8]);
        float4 p1 = *(const float4*)(&pe_t[w*32 + sub*8 + 4]);
        sc[w] = qa.x*p0.x + qa.y*p0.y + qa.z*p0.z + qa.w*p0.w
              + qc.x*p1.x + qc.y*p1.y + qc.z*p1.z + qc.w*p1.w;
    }

    int d = sv / 576; int rem = sv - d*576; int h = rem / 24; int w0 = rem - h*24;

    // validity mask (bit per window slot)
    unsigned vm = 0;
    {
        int widx = 0;
        #pragma unroll
        for (int di = -1; di <= 1; di++)
        #pragma unroll
        for (int dj = -1; dj <= 1; dj++)
        #pragma unroll
        for (int dl = -1; dl <= 1; dl++) {
            int dd = d+di, hh = h+dj, ww = w0+dl;
            if (((unsigned)dd < 24u) & ((unsigned)hh < 24u) & ((unsigned)ww < 24u))
                vm |= 1u << widx;
            widx++;
        }
    }

    // QK: partial dot over 8 channels, coalesced float4 loads
    {
        int widx = 0;
        #pragma unroll
        for (int di = -1; di <= 1; di++)
        #pragma unroll
        for (int dj = -1; dj <= 1; dj++)
        #pragma unroll
        for (int dl = -1; dl <= 1; dl++) {
            if (vm & (1u << widx)) {
                const float* kp = kb + (size_t)(sv + di*576 + dj*24 + dl)*HDIM + sub*8;
                float4 k0 = *(const float4*)(kp);
                float4 k1 = *(const float4*)(kp + 4);
                sc[widx] += qa.x*k0.x + qa.y*k0.y + qa.z*k0.z + qa.w*k0.w
                          + qc.x*k1.x + qc.y*k1.y + qc.z*k1.z + qc.w*k1.w;
            }
            widx++;
        }
    }

    // reduce partials across the 4-lane group (bitwise-identical in all lanes)
    #pragma unroll
    for (int w = 0; w < 27; w++) {
        sc[w] += __shfl_xor(sc[w], 1);
        sc[w] += __shfl_xor(sc[w], 2);
    }

    const float scale = 0.17677669529663687f;   // 32^-0.5
    float mx = -1e30f;
    #pragma unroll
    for (int w = 0; w < 27; w++) {
        sc[w] *= scale;
        mx = fmaxf(mx, sc[w]);
    }
    float sum = 0.f;
    #pragma unroll
    for (int w = 0; w < 27; w++) {
        float e = __expf(sc[w] - mx);
        sc[w] = e;
        sum += e;
    }
    float inv = 1.f / sum;

    // PV: accumulate this lane's 8 channels
    float o[8];
    #pragma unroll
    for (int i = 0; i < 8; i++) o[i] = 0.f;
    {
        int widx = 0;
        #pragma unroll
        for (int di = -1; di <= 1; di++)
        #pragma unroll
        for (int dj = -1; dj <= 1; dj++)
        #pragma unroll
        for (int dl = -1; dl <= 1; dl++) {
            if (vm & (1u << widx)) {
                float p = sc[widx];
                const float* vp = vb + (size_t)(sv + di*576 + dj*24 + dl)*HDIM + sub*8;
                float4 v0 = *(const float4*)(vp);
                float4 v1 = *(const float4*)(vp + 4);
                o[0] += p*v0.x; o[1] += p*v0.y; o[2] += p*v0.z; o[3] += p*v0.w;
                o[4] += p*v1.x; o[5] += p*v1.y; o[6] += p*v1.z; o[7] += p*v1.w;
            }
            widx++;
        }
    }

    // transpose via LDS, then coalesced store to [b][c][s]
    #pragma unroll
    for (int i = 0; i < 8; i++)
        ot[vloc*33 + sub*8 + i] = o[i] * inv;
    __syncthreads();

    #pragma unroll
    for (int r = 0; r < 8; r++) {
        int idx = t + r*256;          // 0..2047
        int c  = idx >> 6;            // 0..31
        int vl = idx & 63;
        aout[((size_t)b*CIN + n*HDIM + c)*SVOX + s0 + vl] = ot[vl*33 + c];
    }
}

// ---------------------------------------------------------------------------
// Kernel 3: output projection GEMM.
//   Xa [B][128][S], W [128][128], out [B][128][S]
// ---------------------------------------------------------------------------
__global__ __launch_bounds__(256) void proj_gemm_kernel(
    const float* __restrict__ X,
    const float* __restrict__ W,
    const float* __restrict__ bias,
    float* __restrict__ out)
{
    __shared__ float smem[128*64 + 64*68];
    float* Xs = smem;
    float* Ws = smem + 128*64;

    int t  = threadIdx.x;
    int s0 = blockIdx.x * 64;
    int o0 = blockIdx.y * 64;
    int b  = blockIdx.z;

    const float* Xg = X + (size_t)b*CIN*SVOX + s0;
    #pragma unroll
    for (int k2 = 0; k2 < 8; k2++) {
        int idx = t + k2*256;
        int c = idx >> 4, sv4 = idx & 15;
        *(float4*)(&Xs[c*64 + sv4*4]) = *(const float4*)(Xg + (size_t)c*SVOX + sv4*4);
    }

    int tx = t & 15, ty = t >> 4;
    float acc[4][4] = {{0.f,0.f,0.f,0.f},{0.f,0.f,0.f,0.f},{0.f,0.f,0.f,0.f},{0.f,0.f,0.f,0.f}};

    for (int kk = 0; kk < 2; kk++) {
        __syncthreads();
        #pragma unroll
        for (int k2 = 0; k2 < 4; k2++) {
            int idx = t + k2*256;
            int o = idx >> 4, cv4 = idx & 15;
            *(float4*)(&Ws[o*68 + cv4*4]) =
                *(const float4*)(W + (size_t)(o0+o)*CIN + kk*64 + cv4*4);
        }
        __syncthreads();
        #pragma unroll
        for (int c4 = 0; c4 < 16; c4++) {
            float4 wq[4];
            #pragma unroll
            for (int i = 0; i < 4; i++)
                wq[i] = *(const float4*)(&Ws[(ty*4+i)*68 + c4*4]);
            int cb = kk*64 + c4*4;
            float4 xq[4];
            #pragma unroll
            for (int r = 0; r < 4; r++)
                xq[r] = *(const float4*)(&Xs[(cb+r)*64 + tx*4]);
            const float* wf = (const float*)wq;
            const float* xf = (const float*)xq;
            #pragma unroll
            for (int i = 0; i < 4; i++)
                #pragma unroll
                for (int cc = 0; cc < 4; cc++)
                    #pragma unroll
                    for (int j = 0; j < 4; j++)
                        acc[i][j] += wf[i*4+cc] * xf[cc*4+j];
        }
    }

    float* dstB = out + ((size_t)b*CIN + o0 + ty*4)*SVOX + s0 + tx*4;
    #pragma unroll
    for (int i = 0; i < 4; i++) {
        float bi = bias[o0 + ty*4 + i];
        float4 v;
        v.x = acc[i][0] + bi; v.y = acc[i][1] + bi;
        v.z = acc[i][2] + bi; v.w = acc[i][3] + bi;
        *(float4*)(dstB + (size_t)i*SVOX) = v;
    }
}

extern "C" void kernel_launch(void* const* d_in, const int* in_sizes, int n_in,
                              void* d_out, int out_size, void* d_ws, size_t ws_size,
                              hipStream_t stream) {
    const float* x      = (const float*)d_in[0];
    const float* qkv_w  = (const float*)d_in[1];
    const float* qkv_b  = (const float*)d_in[2];
    const float* proj_w = (const float*)d_in[3];
    const float* proj_b = (const float*)d_in[4];
    const float* pos    = (const float*)d_in[5];
    float* out = (float*)d_out;

    float* qkv_t  = (float*)d_ws;                               // [2][3][4][S][32]
    float* attn_o = qkv_t + (size_t)2*3*NHEAD*SVOX*HDIM;        // [2][128][S]

    qkv_gemm_kernel<<<dim3(SVOX/64, 384/64, 2), 256, 0, stream>>>(x, qkv_w, qkv_b, qkv_t);
    attn_kernel<<<dim3(SVOX/64, NHEAD, 2), 256, 0, stream>>>(qkv_t, pos, attn_o);
    proj_gemm_kernel<<<dim3(SVOX/64, CIN/64, 2), 256, 0, stream>>>(attn_o, proj_w, proj_b, out);
}

// Round 3
// 87.175 us; speedup vs baseline: 4.6622x; 1.3232x over previous
//
#include <hip/hip_runtime.h>
#include <hip/hip_bf16.h>

#define SVOX 13824   // 24*24*24
#define CIN 128
#define NHEAD 4
#define HDIM 32

typedef __attribute__((ext_vector_type(8))) short short8;
typedef __attribute__((ext_vector_type(4))) float f32x4;
typedef __attribute__((ext_vector_type(4))) unsigned int uint4v;

__device__ __forceinline__ unsigned short f2bf(float x) {
    unsigned u = __float_as_uint(x);
    u += 0x7FFFu + ((u >> 16) & 1u);
    return (unsigned short)(u >> 16);
}
__device__ __forceinline__ float bf2f(unsigned short s) {
    return __uint_as_float(((unsigned)s) << 16);
}
__device__ __forceinline__ unsigned packhl(float x) {
    unsigned short h = f2bf(x);
    unsigned short l = f2bf(x - bf2f(h));
    return (unsigned)h | ((unsigned)l << 16);
}

// ---------------------------------------------------------------------------
// MFMA GEMM, bf16x3 error-compensated split (error ~2^-16, effectively f32).
//   out[o][s] = sum_c W[o][c] * X[b][c][s] + bias[o]
// Tile: 64 (o) x 64 (s), K=128 in 2 chunks of 64. 4 waves, 32x32 each.
// MODE 0: epilogue scatters to qkv_t [B][3][4][S][32]
// MODE 1: epilogue writes [B][128][S] directly
// ---------------------------------------------------------------------------
template<int MODE>
__global__ __launch_bounds__(256) void gemm_mfma(
    const float* __restrict__ X,
    const float* __restrict__ W,
    const float* __restrict__ bias,
    float* __restrict__ out)
{
    __shared__ __align__(16) unsigned char smem[52224];
    short*    Wh = (short*)smem;                 // [64][136] bf16 hi
    short*    Wl = (short*)(smem + 17408);       // [64][136] bf16 lo
    unsigned* Xs = (unsigned*)(smem + 34816);    // [64 s][68 k] packed hi|lo<<16
    float*    T  = (float*)smem;                 // epilogue transpose (alias)

    const int t    = threadIdx.x;
    const int s0   = blockIdx.x * 64;
    const int o0   = blockIdx.y * 64;
    const int b    = blockIdx.z;
    const int lane = t & 63;
    const int wid  = t >> 6;
    const int l15  = lane & 15;
    const int g4   = lane >> 4;          // 0..3
    const int wm   = (wid >> 1) * 32;
    const int wn   = (wid & 1) * 32;

    // ---- stage W tile [64][K=128] as hi/lo bf16 planes ----
    #pragma unroll
    for (int i = 0; i < 8; i++) {
        int f = t + i * 256;
        int row = f >> 5, c4 = f & 31;
        float4 w = *(const float4*)(W + (size_t)(o0 + row) * CIN + c4 * 4);
        unsigned short h0 = f2bf(w.x), h1 = f2bf(w.y), h2 = f2bf(w.z), h3 = f2bf(w.w);
        unsigned short l0 = f2bf(w.x - bf2f(h0)), l1 = f2bf(w.y - bf2f(h1));
        unsigned short l2 = f2bf(w.z - bf2f(h2)), l3 = f2bf(w.w - bf2f(h3));
        uint2 ph; ph.x = (unsigned)h0 | ((unsigned)h1 << 16); ph.y = (unsigned)h2 | ((unsigned)h3 << 16);
        uint2 pl; pl.x = (unsigned)l0 | ((unsigned)l1 << 16); pl.y = (unsigned)l2 | ((unsigned)l3 << 16);
        *(uint2*)(Wh + row * 136 + c4 * 4) = ph;
        *(uint2*)(Wl + row * 136 + c4 * 4) = pl;
    }

    f32x4 acc[2][2];
    #pragma unroll
    for (int mf = 0; mf < 2; mf++)
        #pragma unroll
        for (int nf = 0; nf < 2; nf++)
            acc[mf][nf] = (f32x4){0.f, 0.f, 0.f, 0.f};

    const int sx = t & 63;   // this thread's s for X staging
    const int kg = t >> 6;   // k-group of 16

    for (int chunk = 0; chunk < 2; chunk++) {
        __syncthreads();
        // ---- stage X chunk [k=64][s=64] -> Xs[s][k] packed ----
        unsigned pk[16];
        #pragma unroll
        for (int i = 0; i < 16; i++) {
            int k = kg * 16 + i;
            float x = X[((size_t)b * CIN + chunk * 64 + k) * SVOX + s0 + sx];
            pk[i] = packhl(x);
        }
        #pragma unroll
        for (int j = 0; j < 4; j++) {
            uint4v v;
            v.x = pk[4 * j + 0]; v.y = pk[4 * j + 1];
            v.z = pk[4 * j + 2]; v.w = pk[4 * j + 3];
            *(uint4v*)(Xs + sx * 68 + kg * 16 + 4 * j) = v;
        }
        __syncthreads();

        // ---- A fragments for this chunk (hoisted) ----
        short8 Ah[2][2], Al[2][2];   // [ks][mf]
        #pragma unroll
        for (int ks = 0; ks < 2; ks++)
            #pragma unroll
            for (int mf = 0; mf < 2; mf++) {
                int off = (wm + mf * 16 + l15) * 136 + chunk * 64 + ks * 32 + g4 * 8;
                Ah[ks][mf] = *(const short8*)(Wh + off);
                Al[ks][mf] = *(const short8*)(Wl + off);
            }

        #pragma unroll
        for (int ks = 0; ks < 2; ks++) {
            short8 Bh[2], Bl[2];
            #pragma unroll
            for (int nf = 0; nf < 2; nf++) {
                const uint4v* p = (const uint4v*)(Xs + (wn + nf * 16 + l15) * 68 + ks * 32 + g4 * 8);
                uint4v r0 = p[0], r1 = p[1];
                uint4v hv, lv;
                hv.x = __builtin_amdgcn_perm(r0.y, r0.x, 0x05040100u);
                hv.y = __builtin_amdgcn_perm(r0.w, r0.z, 0x05040100u);
                hv.z = __builtin_amdgcn_perm(r1.y, r1.x, 0x05040100u);
                hv.w = __builtin_amdgcn_perm(r1.w, r1.z, 0x05040100u);
                lv.x = __builtin_amdgcn_perm(r0.y, r0.x, 0x07060302u);
                lv.y = __builtin_amdgcn_perm(r0.w, r0.z, 0x07060302u);
                lv.z = __builtin_amdgcn_perm(r1.y, r1.x, 0x07060302u);
                lv.w = __builtin_amdgcn_perm(r1.w, r1.z, 0x07060302u);
                Bh[nf] = __builtin_bit_cast(short8, hv);
                Bl[nf] = __builtin_bit_cast(short8, lv);
            }
            #pragma unroll
            for (int mf = 0; mf < 2; mf++)
                #pragma unroll
                for (int nf = 0; nf < 2; nf++) {
                    acc[mf][nf] = __builtin_amdgcn_mfma_f32_16x16x32_bf16(Ah[ks][mf], Bh[nf], acc[mf][nf], 0, 0, 0);
                    acc[mf][nf] = __builtin_amdgcn_mfma_f32_16x16x32_bf16(Ah[ks][mf], Bl[nf], acc[mf][nf], 0, 0, 0);
                    acc[mf][nf] = __builtin_amdgcn_mfma_f32_16x16x32_bf16(Al[ks][mf], Bh[nf], acc[mf][nf], 0, 0, 0);
                }
        }
    }

    __syncthreads();   // done with W/X LDS; reuse as T

    if (MODE == 0) {
        // T[s][m], stride 68 -> vector along m (= ic)
        #pragma unroll
        for (int mf = 0; mf < 2; mf++)
            #pragma unroll
            for (int nf = 0; nf < 2; nf++) {
                int s  = wn + nf * 16 + l15;
                int mb = wm + mf * 16 + g4 * 4;
                *(f32x4*)(T + s * 68 + mb) = acc[mf][nf];
            }
        __syncthreads();
        #pragma unroll
        for (int i = 0; i < 4; i++) {
            int f = t + i * 256;
            int og = f & 15, sl = f >> 4;
            float4 v = *(float4*)(T + sl * 68 + og * 4);
            int o_g = o0 + og * 4;
            v.x += bias[o_g]; v.y += bias[o_g + 1]; v.z += bias[o_g + 2]; v.w += bias[o_g + 3];
            int part = o_g >> 7, head = (o_g >> 5) & 3, ic = o_g & 31;
            float* dst = out + ((((size_t)b * 3 + part) * NHEAD + head) * SVOX + s0 + sl) * HDIM + ic;
            *(float4*)dst = v;
        }
    } else {
        // T[m][s], stride 72 -> vector along s
        #pragma unroll
        for (int mf = 0; mf < 2; mf++)
            #pragma unroll
            for (int nf = 0; nf < 2; nf++) {
                int s  = wn + nf * 16 + l15;
                int mb = wm + mf * 16 + g4 * 4;
                #pragma unroll
                for (int r = 0; r < 4; r++)
                    T[(mb + r) * 72 + s] = acc[mf][nf][r];
            }
        __syncthreads();
        #pragma unroll
        for (int i = 0; i < 4; i++) {
            int f = t + i * 256;
            int s4 = f & 15, m = f >> 4;
            float4 v = *(float4*)(T + m * 72 + s4 * 4);
            float bi = bias[o0 + m];
            v.x += bi; v.y += bi; v.z += bi; v.w += bi;
            *(float4*)(out + ((size_t)b * CIN + o0 + m) * SVOX + s0 + s4 * 4) = v;
        }
    }
}

// ---------------------------------------------------------------------------
// Windowed 3x3x3 attention, 4 threads per (voxel, head). Unchanged from R2.
// ---------------------------------------------------------------------------
__global__ __launch_bounds__(256) void attn_kernel(
    const float* __restrict__ qkv,
    const float* __restrict__ pos,
    float* __restrict__ aout)
{
    __shared__ float pe_t[27*32];   // pos transposed: [w][c]
    __shared__ float ot[64*33];     // output transpose buffer

    int t = threadIdx.x;
    for (int i = t; i < 27*32; i += 256) {
        int w = i >> 5, c = i & 31;
        pe_t[i] = pos[c*27 + w];
    }
    __syncthreads();

    int vloc = t >> 2;
    int sub  = t & 3;
    int s0   = blockIdx.x * 64;
    int sv   = s0 + vloc;
    int n    = blockIdx.y;
    int b    = blockIdx.z;

    const float* qb = qkv + (((size_t)b*3 + 0)*NHEAD + n)*(size_t)SVOX*HDIM;
    const float* kb = qkv + (((size_t)b*3 + 1)*NHEAD + n)*(size_t)SVOX*HDIM;
    const float* vb = qkv + (((size_t)b*3 + 2)*NHEAD + n)*(size_t)SVOX*HDIM;

    const float* qp = qb + (size_t)sv*HDIM + sub*8;
    float4 qa = *(const float4*)(qp);
    float4 qc = *(const float4*)(qp + 4);

    float sc[27];
    #pragma unroll
    for (int w = 0; w < 27; w++) {
        float4 p0 = *(const float4*)(&pe_t[w*32 + sub*8]);
        float4 p1 = *(const float4*)(&pe_t[w*32 + sub*8 + 4]);
        sc[w] = qa.x*p0.x + qa.y*p0.y + qa.z*p0.z + qa.w*p0.w
              + qc.x*p1.x + qc.y*p1.y + qc.z*p1.z + qc.w*p1.w;
    }

    int d = sv / 576; int rem = sv - d*576; int h = rem / 24; int w0 = rem - h*24;

    unsigned vm = 0;
    {
        int widx = 0;
        #pragma unroll
        for (int di = -1; di <= 1; di++)
        #pragma unroll
        for (int dj = -1; dj <= 1; dj++)
        #pragma unroll
        for (int dl = -1; dl <= 1; dl++) {
            int dd = d+di, hh = h+dj, ww = w0+dl;
            if (((unsigned)dd < 24u) & ((unsigned)hh < 24u) & ((unsigned)ww < 24u))
                vm |= 1u << widx;
            widx++;
        }
    }

    {
        int widx = 0;
        #pragma unroll
        for (int di = -1; di <= 1; di++)
        #pragma unroll
        for (int dj = -1; dj <= 1; dj++)
        #pragma unroll
        for (int dl = -1; dl <= 1; dl++) {
            if (vm & (1u << widx)) {
                const float* kp = kb + (size_t)(sv + di*576 + dj*24 + dl)*HDIM + sub*8;
                float4 k0 = *(const float4*)(kp);
                float4 k1 = *(const float4*)(kp + 4);
                sc[widx] += qa.x*k0.x + qa.y*k0.y + qa.z*k0.z + qa.w*k0.w
                          + qc.x*k1.x + qc.y*k1.y + qc.z*k1.z + qc.w*k1.w;
            }
            widx++;
        }
    }

    #pragma unroll
    for (int w = 0; w < 27; w++) {
        sc[w] += __shfl_xor(sc[w], 1);
        sc[w] += __shfl_xor(sc[w], 2);
    }

    const float scale = 0.17677669529663687f;
    float mx = -1e30f;
    #pragma unroll
    for (int w = 0; w < 27; w++) {
        sc[w] *= scale;
        mx = fmaxf(mx, sc[w]);
    }
    float sum = 0.f;
    #pragma unroll
    for (int w = 0; w < 27; w++) {
        float e = __expf(sc[w] - mx);
        sc[w] = e;
        sum += e;
    }
    float inv = 1.f / sum;

    float o[8];
    #pragma unroll
    for (int i = 0; i < 8; i++) o[i] = 0.f;
    {
        int widx = 0;
        #pragma unroll
        for (int di = -1; di <= 1; di++)
        #pragma unroll
        for (int dj = -1; dj <= 1; dj++)
        #pragma unroll
        for (int dl = -1; dl <= 1; dl++) {
            if (vm & (1u << widx)) {
                float p = sc[widx];
                const float* vp = vb + (size_t)(sv + di*576 + dj*24 + dl)*HDIM + sub*8;
                float4 v0 = *(const float4*)(vp);
                float4 v1 = *(const float4*)(vp + 4);
                o[0] += p*v0.x; o[1] += p*v0.y; o[2] += p*v0.z; o[3] += p*v0.w;
                o[4] += p*v1.x; o[5] += p*v1.y; o[6] += p*v1.z; o[7] += p*v1.w;
            }
            widx++;
        }
    }

    #pragma unroll
    for (int i = 0; i < 8; i++)
        ot[vloc*33 + sub*8 + i] = o[i] * inv;
    __syncthreads();

    #pragma unroll
    for (int r = 0; r < 8; r++) {
        int idx = t + r*256;
        int c  = idx >> 6;
        int vl = idx & 63;
        aout[((size_t)b*CIN + n*HDIM + c)*SVOX + s0 + vl] = ot[vl*33 + c];
    }
}

extern "C" void kernel_launch(void* const* d_in, const int* in_sizes, int n_in,
                              void* d_out, int out_size, void* d_ws, size_t ws_size,
                              hipStream_t stream) {
    const float* x      = (const float*)d_in[0];
    const float* qkv_w  = (const float*)d_in[1];
    const float* qkv_b  = (const float*)d_in[2];
    const float* proj_w = (const float*)d_in[3];
    const float* proj_b = (const float*)d_in[4];
    const float* pos    = (const float*)d_in[5];
    float* out = (float*)d_out;

    float* qkv_t  = (float*)d_ws;                               // [2][3][4][S][32]
    float* attn_o = qkv_t + (size_t)2*3*NHEAD*SVOX*HDIM;        // [2][128][S]

    gemm_mfma<0><<<dim3(SVOX/64, 384/64, 2), 256, 0, stream>>>(x, qkv_w, qkv_b, qkv_t);
    attn_kernel<<<dim3(SVOX/64, NHEAD, 2), 256, 0, stream>>>(qkv_t, pos, attn_o);
    gemm_mfma<1><<<dim3(SVOX/64, CIN/64, 2), 256, 0, stream>>>(attn_o, proj_w, proj_b, out);
}

// Round 4
// 75.615 us; speedup vs baseline: 5.3750x; 1.1529x over previous
//
#include <hip/hip_runtime.h>
#include <hip/hip_bf16.h>

#define SVOX 13824   // 24*24*24
#define CIN 128
#define NHEAD 4
#define HDIM 32

typedef __attribute__((ext_vector_type(8))) short short8;
typedef __attribute__((ext_vector_type(4))) float f32x4;
typedef __attribute__((ext_vector_type(4))) unsigned int uint4v;

__device__ __forceinline__ unsigned short f2bf(float x) {
    unsigned u = __float_as_uint(x);
    u += 0x7FFFu + ((u >> 16) & 1u);
    return (unsigned short)(u >> 16);
}
__device__ __forceinline__ float bf2f(unsigned short s) {
    return __uint_as_float(((unsigned)s) << 16);
}
__device__ __forceinline__ unsigned packhl(float x) {
    unsigned short h = f2bf(x);
    unsigned short l = f2bf(x - bf2f(h));
    return (unsigned)h | ((unsigned)l << 16);
}

// ---------------------------------------------------------------------------
// MFMA GEMM, bf16x3 error-compensated split (error ~2^-16, effectively f32).
//   out[o][s] = sum_c W[o][c] * X[b][c][s] + bias[o]
// Tile: 64 (o) x 64 (s), K=128 in 2 chunks of 64. 4 waves, 32x32 each.
// MODE 0: epilogue scatters to qkv_t [B][3][4][S][32]
// MODE 1: epilogue writes [B][128][S] directly
// ---------------------------------------------------------------------------
template<int MODE>
__global__ __launch_bounds__(256) void gemm_mfma(
    const float* __restrict__ X,
    const float* __restrict__ W,
    const float* __restrict__ bias,
    float* __restrict__ out)
{
    __shared__ __align__(16) unsigned char smem[52224];
    short*    Wh = (short*)smem;                 // [64][136] bf16 hi
    short*    Wl = (short*)(smem + 17408);       // [64][136] bf16 lo
    unsigned* Xs = (unsigned*)(smem + 34816);    // [64 s][68 k] packed hi|lo<<16
    float*    T  = (float*)smem;                 // epilogue transpose (alias)

    const int t    = threadIdx.x;
    const int s0   = blockIdx.x * 64;
    const int o0   = blockIdx.y * 64;
    const int b    = blockIdx.z;
    const int lane = t & 63;
    const int wid  = t >> 6;
    const int l15  = lane & 15;
    const int g4   = lane >> 4;          // 0..3
    const int wm   = (wid >> 1) * 32;
    const int wn   = (wid & 1) * 32;

    // ---- stage W tile [64][K=128] as hi/lo bf16 planes ----
    #pragma unroll
    for (int i = 0; i < 8; i++) {
        int f = t + i * 256;
        int row = f >> 5, c4 = f & 31;
        float4 w = *(const float4*)(W + (size_t)(o0 + row) * CIN + c4 * 4);
        unsigned short h0 = f2bf(w.x), h1 = f2bf(w.y), h2 = f2bf(w.z), h3 = f2bf(w.w);
        unsigned short l0 = f2bf(w.x - bf2f(h0)), l1 = f2bf(w.y - bf2f(h1));
        unsigned short l2 = f2bf(w.z - bf2f(h2)), l3 = f2bf(w.w - bf2f(h3));
        uint2 ph; ph.x = (unsigned)h0 | ((unsigned)h1 << 16); ph.y = (unsigned)h2 | ((unsigned)h3 << 16);
        uint2 pl; pl.x = (unsigned)l0 | ((unsigned)l1 << 16); pl.y = (unsigned)l2 | ((unsigned)l3 << 16);
        *(uint2*)(Wh + row * 136 + c4 * 4) = ph;
        *(uint2*)(Wl + row * 136 + c4 * 4) = pl;
    }

    f32x4 acc[2][2];
    #pragma unroll
    for (int mf = 0; mf < 2; mf++)
        #pragma unroll
        for (int nf = 0; nf < 2; nf++)
            acc[mf][nf] = (f32x4){0.f, 0.f, 0.f, 0.f};

    const int sx = t & 63;   // this thread's s for X staging
    const int kg = t >> 6;   // k-group of 16

    for (int chunk = 0; chunk < 2; chunk++) {
        __syncthreads();
        // ---- stage X chunk [k=64][s=64] -> Xs[s][k] packed ----
        unsigned pk[16];
        #pragma unroll
        for (int i = 0; i < 16; i++) {
            int k = kg * 16 + i;
            float x = X[((size_t)b * CIN + chunk * 64 + k) * SVOX + s0 + sx];
            pk[i] = packhl(x);
        }
        #pragma unroll
        for (int j = 0; j < 4; j++) {
            uint4v v;
            v.x = pk[4 * j + 0]; v.y = pk[4 * j + 1];
            v.z = pk[4 * j + 2]; v.w = pk[4 * j + 3];
            *(uint4v*)(Xs + sx * 68 + kg * 16 + 4 * j) = v;
        }
        __syncthreads();

        // ---- A fragments for this chunk (hoisted) ----
        short8 Ah[2][2], Al[2][2];   // [ks][mf]
        #pragma unroll
        for (int ks = 0; ks < 2; ks++)
            #pragma unroll
            for (int mf = 0; mf < 2; mf++) {
                int off = (wm + mf * 16 + l15) * 136 + chunk * 64 + ks * 32 + g4 * 8;
                Ah[ks][mf] = *(const short8*)(Wh + off);
                Al[ks][mf] = *(const short8*)(Wl + off);
            }

        #pragma unroll
        for (int ks = 0; ks < 2; ks++) {
            short8 Bh[2], Bl[2];
            #pragma unroll
            for (int nf = 0; nf < 2; nf++) {
                const uint4v* p = (const uint4v*)(Xs + (wn + nf * 16 + l15) * 68 + ks * 32 + g4 * 8);
                uint4v r0 = p[0], r1 = p[1];
                uint4v hv, lv;
                hv.x = __builtin_amdgcn_perm(r0.y, r0.x, 0x05040100u);
                hv.y = __builtin_amdgcn_perm(r0.w, r0.z, 0x05040100u);
                hv.z = __builtin_amdgcn_perm(r1.y, r1.x, 0x05040100u);
                hv.w = __builtin_amdgcn_perm(r1.w, r1.z, 0x05040100u);
                lv.x = __builtin_amdgcn_perm(r0.y, r0.x, 0x07060302u);
                lv.y = __builtin_amdgcn_perm(r0.w, r0.z, 0x07060302u);
                lv.z = __builtin_amdgcn_perm(r1.y, r1.x, 0x07060302u);
                lv.w = __builtin_amdgcn_perm(r1.w, r1.z, 0x07060302u);
                Bh[nf] = __builtin_bit_cast(short8, hv);
                Bl[nf] = __builtin_bit_cast(short8, lv);
            }
            #pragma unroll
            for (int mf = 0; mf < 2; mf++)
                #pragma unroll
                for (int nf = 0; nf < 2; nf++) {
                    acc[mf][nf] = __builtin_amdgcn_mfma_f32_16x16x32_bf16(Ah[ks][mf], Bh[nf], acc[mf][nf], 0, 0, 0);
                    acc[mf][nf] = __builtin_amdgcn_mfma_f32_16x16x32_bf16(Ah[ks][mf], Bl[nf], acc[mf][nf], 0, 0, 0);
                    acc[mf][nf] = __builtin_amdgcn_mfma_f32_16x16x32_bf16(Al[ks][mf], Bh[nf], acc[mf][nf], 0, 0, 0);
                }
        }
    }

    __syncthreads();   // done with W/X LDS; reuse as T

    if (MODE == 0) {
        // T[s][m], stride 68 -> vector along m (= ic)
        #pragma unroll
        for (int mf = 0; mf < 2; mf++)
            #pragma unroll
            for (int nf = 0; nf < 2; nf++) {
                int s  = wn + nf * 16 + l15;
                int mb = wm + mf * 16 + g4 * 4;
                *(f32x4*)(T + s * 68 + mb) = acc[mf][nf];
            }
        __syncthreads();
        #pragma unroll
        for (int i = 0; i < 4; i++) {
            int f = t + i * 256;
            int og = f & 15, sl = f >> 4;
            float4 v = *(float4*)(T + sl * 68 + og * 4);
            int o_g = o0 + og * 4;
            v.x += bias[o_g]; v.y += bias[o_g + 1]; v.z += bias[o_g + 2]; v.w += bias[o_g + 3];
            int part = o_g >> 7, head = (o_g >> 5) & 3, ic = o_g & 31;
            float* dst = out + ((((size_t)b * 3 + part) * NHEAD + head) * SVOX + s0 + sl) * HDIM + ic;
            *(float4*)dst = v;
        }
    } else {
        // T[m][s], stride 72 -> vector along s
        #pragma unroll
        for (int mf = 0; mf < 2; mf++)
            #pragma unroll
            for (int nf = 0; nf < 2; nf++) {
                int s  = wn + nf * 16 + l15;
                int mb = wm + mf * 16 + g4 * 4;
                #pragma unroll
                for (int r = 0; r < 4; r++)
                    T[(mb + r) * 72 + s] = acc[mf][nf][r];
            }
        __syncthreads();
        #pragma unroll
        for (int i = 0; i < 4; i++) {
            int f = t + i * 256;
            int s4 = f & 15, m = f >> 4;
            float4 v = *(float4*)(T + m * 72 + s4 * 4);
            float bi = bias[o0 + m];
            v.x += bi; v.y += bi; v.z += bi; v.w += bi;
            *(float4*)(out + ((size_t)b * CIN + o0 + m) * SVOX + s0 + s4 * 4) = v;
        }
    }
}

// ---------------------------------------------------------------------------
// Windowed 3x3x3 attention, 4 threads per (voxel, head).
// Branch-free: invalid window slots load a clamped address (offset 0) and
// their contribution is masked with cndmask. Loads issued in batches of 9
// slots (18 float4 in flight) for deep memory-level parallelism.
// ---------------------------------------------------------------------------
__global__ __launch_bounds__(256) void attn_kernel(
    const float* __restrict__ qkv,
    const float* __restrict__ pos,
    float* __restrict__ aout)
{
    __shared__ float pe_t[27*32];   // pos transposed: [w][c]
    __shared__ float ot[64*33];     // output transpose buffer

    int t = threadIdx.x;
    for (int i = t; i < 27*32; i += 256) {
        int w = i >> 5, c = i & 31;
        pe_t[i] = pos[c*27 + w];
    }
    __syncthreads();

    int vloc = t >> 2;
    int sub  = t & 3;
    int s0   = blockIdx.x * 64;
    int sv   = s0 + vloc;
    int n    = blockIdx.y;
    int b    = blockIdx.z;

    const float* qb = qkv + (((size_t)b*3 + 0)*NHEAD + n)*(size_t)SVOX*HDIM;
    const float* kb = qkv + (((size_t)b*3 + 1)*NHEAD + n)*(size_t)SVOX*HDIM;
    const float* vb = qkv + (((size_t)b*3 + 2)*NHEAD + n)*(size_t)SVOX*HDIM;

    const float* qp = qb + (size_t)sv*HDIM + sub*8;
    float4 qa = *(const float4*)(qp);
    float4 qc = *(const float4*)(qp + 4);

    // window offsets: (di*576 + dj*24 + dl) for di,dj,dl in {-1,0,1}
    const int doff[27] = {
        -601,-600,-599,-577,-576,-575,-553,-552,-551,
         -25, -24, -23,  -1,   0,   1,  23,  24,  25,
         551, 552, 553, 575, 576, 577, 599, 600, 601
    };

    // validity mask
    int d = sv / 576; int rem = sv - d*576; int h = rem / 24; int w0 = rem - h*24;
    unsigned vm = 0;
    {
        int widx = 0;
        #pragma unroll
        for (int di = -1; di <= 1; di++)
        #pragma unroll
        for (int dj = -1; dj <= 1; dj++)
        #pragma unroll
        for (int dl = -1; dl <= 1; dl++) {
            int dd = d+di, hh = h+dj, ww = w0+dl;
            if (((unsigned)dd < 24u) & ((unsigned)hh < 24u) & ((unsigned)ww < 24u))
                vm |= 1u << widx;
            widx++;
        }
    }

    // partial scores: q . pos_embed over this lane's 8 channels
    float sc[27];
    #pragma unroll
    for (int w = 0; w < 27; w++) {
        float4 p0 = *(const float4*)(&pe_t[w*32 + sub*8]);
        float4 p1 = *(const float4*)(&pe_t[w*32 + sub*8 + 4]);
        sc[w] = qa.x*p0.x + qa.y*p0.y + qa.z*p0.z + qa.w*p0.w
              + qc.x*p1.x + qc.y*p1.y + qc.z*p1.z + qc.w*p1.w;
    }

    // QK: batched branch-free loads (9 slots = 18 float4 in flight)
    #pragma unroll
    for (int g = 0; g < 3; g++) {
        float4 kk[18];
        #pragma unroll
        for (int j = 0; j < 9; j++) {
            int widx = g*9 + j;
            int off = ((vm >> widx) & 1u) ? doff[widx] : 0;
            const float* kp = kb + (size_t)(sv + off)*HDIM + sub*8;
            kk[2*j]   = *(const float4*)(kp);
            kk[2*j+1] = *(const float4*)(kp + 4);
        }
        #pragma unroll
        for (int j = 0; j < 9; j++) {
            int widx = g*9 + j;
            float4 k0 = kk[2*j], k1 = kk[2*j+1];
            float dot = qa.x*k0.x + qa.y*k0.y + qa.z*k0.z + qa.w*k0.w
                      + qc.x*k1.x + qc.y*k1.y + qc.z*k1.z + qc.w*k1.w;
            sc[widx] += ((vm >> widx) & 1u) ? dot : 0.f;
        }
    }

    // reduce partials across the 4-lane group
    #pragma unroll
    for (int w = 0; w < 27; w++) {
        sc[w] += __shfl_xor(sc[w], 1);
        sc[w] += __shfl_xor(sc[w], 2);
    }

    const float scale = 0.17677669529663687f;
    float mx = -1e30f;
    #pragma unroll
    for (int w = 0; w < 27; w++) {
        sc[w] *= scale;
        mx = fmaxf(mx, sc[w]);
    }
    float sum = 0.f;
    #pragma unroll
    for (int w = 0; w < 27; w++) {
        float e = __expf(sc[w] - mx);
        sc[w] = e;
        sum += e;
    }
    float inv = 1.f / sum;

    // PV: same batched branch-free pattern; invalid slots get p=0
    float o[8];
    #pragma unroll
    for (int i = 0; i < 8; i++) o[i] = 0.f;
    #pragma unroll
    for (int g = 0; g < 3; g++) {
        float4 vv[18];
        #pragma unroll
        for (int j = 0; j < 9; j++) {
            int widx = g*9 + j;
            int off = ((vm >> widx) & 1u) ? doff[widx] : 0;
            const float* vp = vb + (size_t)(sv + off)*HDIM + sub*8;
            vv[2*j]   = *(const float4*)(vp);
            vv[2*j+1] = *(const float4*)(vp + 4);
        }
        #pragma unroll
        for (int j = 0; j < 9; j++) {
            int widx = g*9 + j;
            float p = ((vm >> widx) & 1u) ? sc[widx] : 0.f;
            float4 v0 = vv[2*j], v1 = vv[2*j+1];
            o[0] += p*v0.x; o[1] += p*v0.y; o[2] += p*v0.z; o[3] += p*v0.w;
            o[4] += p*v1.x; o[5] += p*v1.y; o[6] += p*v1.z; o[7] += p*v1.w;
        }
    }

    // transpose via LDS, then coalesced store to [b][c][s]
    #pragma unroll
    for (int i = 0; i < 8; i++)
        ot[vloc*33 + sub*8 + i] = o[i] * inv;
    __syncthreads();

    #pragma unroll
    for (int r = 0; r < 8; r++) {
        int idx = t + r*256;
        int c  = idx >> 6;
        int vl = idx & 63;
        aout[((size_t)b*CIN + n*HDIM + c)*SVOX + s0 + vl] = ot[vl*33 + c];
    }
}

extern "C" void kernel_launch(void* const* d_in, const int* in_sizes, int n_in,
                              void* d_out, int out_size, void* d_ws, size_t ws_size,
                              hipStream_t stream) {
    const float* x      = (const float*)d_in[0];
    const float* qkv_w  = (const float*)d_in[1];
    const float* qkv_b  = (const float*)d_in[2];
    const float* proj_w = (const float*)d_in[3];
    const float* proj_b = (const float*)d_in[4];
    const float* pos    = (const float*)d_in[5];
    float* out = (float*)d_out;

    float* qkv_t  = (float*)d_ws;                               // [2][3][4][S][32]
    float* attn_o = qkv_t + (size_t)2*3*NHEAD*SVOX*HDIM;        // [2][128][S]

    gemm_mfma<0><<<dim3(SVOX/64, 384/64, 2), 256, 0, stream>>>(x, qkv_w, qkv_b, qkv_t);
    attn_kernel<<<dim3(SVOX/64, NHEAD, 2), 256, 0, stream>>>(qkv_t, pos, attn_o);
    gemm_mfma<1><<<dim3(SVOX/64, CIN/64, 2), 256, 0, stream>>>(attn_o, proj_w, proj_b, out);
}

// Round 5
// 74.590 us; speedup vs baseline: 5.4488x; 1.0137x over previous
//
#include <hip/hip_runtime.h>
#include <hip/hip_bf16.h>

#define SVOX 13824   // 24*24*24
#define CIN 128
#define NHEAD 4
#define HDIM 32

typedef __attribute__((ext_vector_type(8))) short short8;
typedef __attribute__((ext_vector_type(4))) float f32x4;
typedef __attribute__((ext_vector_type(2))) float f32x2;
typedef __attribute__((ext_vector_type(4))) unsigned int uint4v;
#if defined(__has_builtin)
#if __has_builtin(__builtin_amdgcn_fdot2_f32_bf16)
#define HAVE_DOT2BF 1
typedef __attribute__((ext_vector_type(2))) __bf16 bf16x2;
#endif
#endif

__device__ __forceinline__ unsigned short f2bf(float x) {
    unsigned u = __float_as_uint(x);
    u += 0x7FFFu + ((u >> 16) & 1u);
    return (unsigned short)(u >> 16);
}
__device__ __forceinline__ float bf2f(unsigned short s) {
    return __uint_as_float(((unsigned)s) << 16);
}
__device__ __forceinline__ unsigned packhl(float x) {
    unsigned short h = f2bf(x);
    unsigned short l = f2bf(x - bf2f(h));
    return (unsigned)h | ((unsigned)l << 16);
}

// dot of two bf16 pairs (packed in u32, ch0 low / ch1 high) + acc
__device__ __forceinline__ float dot2bf(unsigned a, unsigned b, float c) {
#ifdef HAVE_DOT2BF
    return __builtin_amdgcn_fdot2_f32_bf16(__builtin_bit_cast(bf16x2, a),
                                           __builtin_bit_cast(bf16x2, b), c, false);
#else
    return __uint_as_float(a << 16) * __uint_as_float(b << 16)
         + __uint_as_float(a & 0xffff0000u) * __uint_as_float(b & 0xffff0000u) + c;
#endif
}

// ---------------------------------------------------------------------------
// MFMA GEMM, bf16x3 error-compensated split (error ~2^-16, effectively f32).
//   out[o][s] = sum_c W[o][c] * X[b][c][s] + bias[o]
// MODE 0: epilogue scatters to q/k (packed bf16) and v (f32), [B][4][S][32]
// MODE 1: epilogue writes [B][128][S] f32 directly
// ---------------------------------------------------------------------------
template<int MODE>
__global__ __launch_bounds__(256) void gemm_mfma(
    const float* __restrict__ X,
    const float* __restrict__ W,
    const float* __restrict__ bias,
    float* __restrict__ out,
    ushort* __restrict__ q_out,
    ushort* __restrict__ k_out,
    float* __restrict__ v_out)
{
    __shared__ __align__(16) unsigned char smem[52224];
    short*    Wh = (short*)smem;                 // [64][136] bf16 hi
    short*    Wl = (short*)(smem + 17408);       // [64][136] bf16 lo
    unsigned* Xs = (unsigned*)(smem + 34816);    // [64 s][68 k] packed hi|lo<<16
    float*    T  = (float*)smem;                 // epilogue transpose (alias)

    const int t    = threadIdx.x;
    const int s0   = blockIdx.x * 64;
    const int o0   = blockIdx.y * 64;
    const int b    = blockIdx.z;
    const int lane = t & 63;
    const int wid  = t >> 6;
    const int l15  = lane & 15;
    const int g4   = lane >> 4;          // 0..3
    const int wm   = (wid >> 1) * 32;
    const int wn   = (wid & 1) * 32;

    // ---- stage W tile [64][K=128] as hi/lo bf16 planes ----
    #pragma unroll
    for (int i = 0; i < 8; i++) {
        int f = t + i * 256;
        int row = f >> 5, c4 = f & 31;
        float4 w = *(const float4*)(W + (size_t)(o0 + row) * CIN + c4 * 4);
        unsigned short h0 = f2bf(w.x), h1 = f2bf(w.y), h2 = f2bf(w.z), h3 = f2bf(w.w);
        unsigned short l0 = f2bf(w.x - bf2f(h0)), l1 = f2bf(w.y - bf2f(h1));
        unsigned short l2 = f2bf(w.z - bf2f(h2)), l3 = f2bf(w.w - bf2f(h3));
        uint2 ph; ph.x = (unsigned)h0 | ((unsigned)h1 << 16); ph.y = (unsigned)h2 | ((unsigned)h3 << 16);
        uint2 pl; pl.x = (unsigned)l0 | ((unsigned)l1 << 16); pl.y = (unsigned)l2 | ((unsigned)l3 << 16);
        *(uint2*)(Wh + row * 136 + c4 * 4) = ph;
        *(uint2*)(Wl + row * 136 + c4 * 4) = pl;
    }

    f32x4 acc[2][2];
    #pragma unroll
    for (int mf = 0; mf < 2; mf++)
        #pragma unroll
        for (int nf = 0; nf < 2; nf++)
            acc[mf][nf] = (f32x4){0.f, 0.f, 0.f, 0.f};

    const int sx = t & 63;   // this thread's s for X staging
    const int kg = t >> 6;   // k-group of 16

    for (int chunk = 0; chunk < 2; chunk++) {
        __syncthreads();
        // ---- stage X chunk [k=64][s=64] -> Xs[s][k] packed ----
        unsigned pk[16];
        #pragma unroll
        for (int i = 0; i < 16; i++) {
            int k = kg * 16 + i;
            float x = X[((size_t)b * CIN + chunk * 64 + k) * SVOX + s0 + sx];
            pk[i] = packhl(x);
        }
        #pragma unroll
        for (int j = 0; j < 4; j++) {
            uint4v v;
            v.x = pk[4 * j + 0]; v.y = pk[4 * j + 1];
            v.z = pk[4 * j + 2]; v.w = pk[4 * j + 3];
            *(uint4v*)(Xs + sx * 68 + kg * 16 + 4 * j) = v;
        }
        __syncthreads();

        // ---- A fragments for this chunk (hoisted) ----
        short8 Ah[2][2], Al[2][2];   // [ks][mf]
        #pragma unroll
        for (int ks = 0; ks < 2; ks++)
            #pragma unroll
            for (int mf = 0; mf < 2; mf++) {
                int off = (wm + mf * 16 + l15) * 136 + chunk * 64 + ks * 32 + g4 * 8;
                Ah[ks][mf] = *(const short8*)(Wh + off);
                Al[ks][mf] = *(const short8*)(Wl + off);
            }

        #pragma unroll
        for (int ks = 0; ks < 2; ks++) {
            short8 Bh[2], Bl[2];
            #pragma unroll
            for (int nf = 0; nf < 2; nf++) {
                const uint4v* p = (const uint4v*)(Xs + (wn + nf * 16 + l15) * 68 + ks * 32 + g4 * 8);
                uint4v r0 = p[0], r1 = p[1];
                uint4v hv, lv;
                hv.x = __builtin_amdgcn_perm(r0.y, r0.x, 0x05040100u);
                hv.y = __builtin_amdgcn_perm(r0.w, r0.z, 0x05040100u);
                hv.z = __builtin_amdgcn_perm(r1.y, r1.x, 0x05040100u);
                hv.w = __builtin_amdgcn_perm(r1.w, r1.z, 0x05040100u);
                lv.x = __builtin_amdgcn_perm(r0.y, r0.x, 0x07060302u);
                lv.y = __builtin_amdgcn_perm(r0.w, r0.z, 0x07060302u);
                lv.z = __builtin_amdgcn_perm(r1.y, r1.x, 0x07060302u);
                lv.w = __builtin_amdgcn_perm(r1.w, r1.z, 0x07060302u);
                Bh[nf] = __builtin_bit_cast(short8, hv);
                Bl[nf] = __builtin_bit_cast(short8, lv);
            }
            #pragma unroll
            for (int mf = 0; mf < 2; mf++)
                #pragma unroll
                for (int nf = 0; nf < 2; nf++) {
                    acc[mf][nf] = __builtin_amdgcn_mfma_f32_16x16x32_bf16(Ah[ks][mf], Bh[nf], acc[mf][nf], 0, 0, 0);
                    acc[mf][nf] = __builtin_amdgcn_mfma_f32_16x16x32_bf16(Ah[ks][mf], Bl[nf], acc[mf][nf], 0, 0, 0);
                    acc[mf][nf] = __builtin_amdgcn_mfma_f32_16x16x32_bf16(Al[ks][mf], Bh[nf], acc[mf][nf], 0, 0, 0);
                }
        }
    }

    __syncthreads();   // done with W/X LDS; reuse as T

    if (MODE == 0) {
        // T[s][m], stride 68 -> vector along m (= ic)
        #pragma unroll
        for (int mf = 0; mf < 2; mf++)
            #pragma unroll
            for (int nf = 0; nf < 2; nf++) {
                int s  = wn + nf * 16 + l15;
                int mb = wm + mf * 16 + g4 * 4;
                *(f32x4*)(T + s * 68 + mb) = acc[mf][nf];
            }
        __syncthreads();
        #pragma unroll
        for (int i = 0; i < 4; i++) {
            int f = t + i * 256;
            int og = f & 15, sl = f >> 4;
            float4 v = *(float4*)(T + sl * 68 + og * 4);
            int o_g = o0 + og * 4;
            v.x += bias[o_g]; v.y += bias[o_g + 1]; v.z += bias[o_g + 2]; v.w += bias[o_g + 3];
            int part = o_g >> 7, pc = o_g & 127;
            int head = pc >> 5, ic = pc & 31;
            size_t base = (((size_t)b * NHEAD + head) * SVOX + s0 + sl) * HDIM + ic;
            if (part == 2) {
                *(float4*)(v_out + base) = v;
            } else {
                ushort4 u;
                u.x = f2bf(v.x); u.y = f2bf(v.y); u.z = f2bf(v.z); u.w = f2bf(v.w);
                *(ushort4*)((part == 0 ? q_out : k_out) + base) = u;
            }
        }
    } else {
        // T[m][s], stride 72 -> vector along s
        #pragma unroll
        for (int mf = 0; mf < 2; mf++)
            #pragma unroll
            for (int nf = 0; nf < 2; nf++) {
                int s  = wn + nf * 16 + l15;
                int mb = wm + mf * 16 + g4 * 4;
                #pragma unroll
                for (int r = 0; r < 4; r++)
                    T[(mb + r) * 72 + s] = acc[mf][nf][r];
            }
        __syncthreads();
        #pragma unroll
        for (int i = 0; i < 4; i++) {
            int f = t + i * 256;
            int s4 = f & 15, m = f >> 4;
            float4 v = *(float4*)(T + m * 72 + s4 * 4);
            float bi = bias[o0 + m];
            v.x += bi; v.y += bi; v.z += bi; v.w += bi;
            *(float4*)(out + ((size_t)b * CIN + o0 + m) * SVOX + s0 + s4 * 4) = v;
        }
    }
}

// ---------------------------------------------------------------------------
// Windowed 3x3x3 attention, 4 threads per (voxel, head).
// Q,K packed bf16 (v_dot2_f32_bf16); V f32 with pk-fma PV. Branch-free
// clamped loads; K batched 9 slots (36 VGPR), V in half-row batches of 9.
// ---------------------------------------------------------------------------
__global__ __launch_bounds__(256, 4) void attn_kernel(
    const ushort* __restrict__ qbf,
    const ushort* __restrict__ kbf,
    const float* __restrict__ vf,
    const float* __restrict__ pos,
    float* __restrict__ aout)
{
    __shared__ __align__(16) unsigned pe_p[27*16];   // pos pairs: [w][cpair]
    __shared__ float ot[64*33];                      // output transpose buffer

    int t = threadIdx.x;
    for (int i = t; i < 27*16; i += 256) {
        int w = i >> 4, cp = i & 15;
        unsigned lo = f2bf(pos[(2*cp)*27 + w]);
        unsigned hi = f2bf(pos[(2*cp+1)*27 + w]);
        pe_p[i] = lo | (hi << 16);
    }
    __syncthreads();

    int vloc = t >> 2;
    int sub  = t & 3;
    int s0   = blockIdx.x * 64;
    int sv   = s0 + vloc;
    int n    = blockIdx.y;
    int b    = blockIdx.z;

    const ushort* kb = kbf + ((size_t)b*NHEAD + n)*(size_t)SVOX*HDIM;
    const float*  vb = vf  + ((size_t)b*NHEAD + n)*(size_t)SVOX*HDIM;

    uint4 qpk = *(const uint4*)(qbf + (((size_t)b*NHEAD + n)*SVOX + sv)*HDIM + sub*8);

    // window offsets: (di*576 + dj*24 + dl)
    const int doff[27] = {
        -601,-600,-599,-577,-576,-575,-553,-552,-551,
         -25, -24, -23,  -1,   0,   1,  23,  24,  25,
         551, 552, 553, 575, 576, 577, 599, 600, 601
    };

    // validity mask
    int d = sv / 576; int rem = sv - d*576; int h = rem / 24; int w0 = rem - h*24;
    unsigned vm = 0;
    {
        int widx = 0;
        #pragma unroll
        for (int di = -1; di <= 1; di++)
        #pragma unroll
        for (int dj = -1; dj <= 1; dj++)
        #pragma unroll
        for (int dl = -1; dl <= 1; dl++) {
            int dd = d+di, hh = h+dj, ww = w0+dl;
            if (((unsigned)dd < 24u) & ((unsigned)hh < 24u) & ((unsigned)ww < 24u))
                vm |= 1u << widx;
            widx++;
        }
    }

    // partial scores: q . pos_embed over this lane's 8 channels
    float sc[27];
    #pragma unroll
    for (int w = 0; w < 27; w++) {
        uint4 pp = *(const uint4*)&pe_p[w*16 + sub*4];
        float s = dot2bf(qpk.x, pp.x, 0.f);
        s = dot2bf(qpk.y, pp.y, s);
        s = dot2bf(qpk.z, pp.z, s);
        s = dot2bf(qpk.w, pp.w, s);
        sc[w] = s;
    }

    // QK: batched branch-free bf16 loads (9 slots = 9 dwordx4 in flight)
    #pragma unroll
    for (int g = 0; g < 3; g++) {
        uint4 kk[9];
        #pragma unroll
        for (int j = 0; j < 9; j++) {
            int widx = g*9 + j;
            int off = ((vm >> widx) & 1u) ? doff[widx] : 0;
            kk[j] = *(const uint4*)(kb + (size_t)(sv + off)*HDIM + sub*8);
        }
        #pragma unroll
        for (int j = 0; j < 9; j++) {
            int widx = g*9 + j;
            float dd = dot2bf(qpk.x, kk[j].x, 0.f);
            dd = dot2bf(qpk.y, kk[j].y, dd);
            dd = dot2bf(qpk.z, kk[j].z, dd);
            dd = dot2bf(qpk.w, kk[j].w, dd);
            sc[widx] += ((vm >> widx) & 1u) ? dd : 0.f;
        }
    }

    // reduce partials across the 4-lane group
    #pragma unroll
    for (int w = 0; w < 27; w++) {
        sc[w] += __shfl_xor(sc[w], 1);
        sc[w] += __shfl_xor(sc[w], 2);
    }

    const float scale = 0.17677669529663687f;
    float mx = -1e30f;
    #pragma unroll
    for (int w = 0; w < 27; w++) {
        sc[w] *= scale;
        mx = fmaxf(mx, sc[w]);
    }
    float sum = 0.f;
    #pragma unroll
    for (int w = 0; w < 27; w++) {
        float e = __expf(sc[w] - mx);
        sc[w] = e;
        sum += e;
    }
    float inv = 1.f / sum;

    // PV: f32 V, half-row batches of 9 slots; invalid slots get p=0
    f32x2 o2[4];
    o2[0] = (f32x2){0.f,0.f}; o2[1] = (f32x2){0.f,0.f};
    o2[2] = (f32x2){0.f,0.f}; o2[3] = (f32x2){0.f,0.f};
    #pragma unroll
    for (int g = 0; g < 3; g++) {
        float pr[9];
        const float* vp[9];
        #pragma unroll
        for (int j = 0; j < 9; j++) {
            int widx = g*9 + j;
            int off = ((vm >> widx) & 1u) ? doff[widx] : 0;
            vp[j] = vb + (size_t)(sv + off)*HDIM + sub*8;
            pr[j] = ((vm >> widx) & 1u) ? sc[widx] : 0.f;
        }
        {
            float4 va[9];
            #pragma unroll
            for (int j = 0; j < 9; j++) va[j] = *(const float4*)(vp[j]);
            #pragma unroll
            for (int j = 0; j < 9; j++) {
                f32x2 pp2 = {pr[j], pr[j]};
                o2[0] += pp2 * (f32x2){va[j].x, va[j].y};
                o2[1] += pp2 * (f32x2){va[j].z, va[j].w};
            }
        }
        {
            float4 vc[9];
            #pragma unroll
            for (int j = 0; j < 9; j++) vc[j] = *(const float4*)(vp[j] + 4);
            #pragma unroll
            for (int j = 0; j < 9; j++) {
                f32x2 pp2 = {pr[j], pr[j]};
                o2[2] += pp2 * (f32x2){vc[j].x, vc[j].y};
                o2[3] += pp2 * (f32x2){vc[j].z, vc[j].w};
            }
        }
    }

    // transpose via LDS, then coalesced store to [b][c][s]
    float oo[8] = {o2[0].x, o2[0].y, o2[1].x, o2[1].y,
                   o2[2].x, o2[2].y, o2[3].x, o2[3].y};
    #pragma unroll
    for (int i = 0; i < 8; i++)
        ot[vloc*33 + sub*8 + i] = oo[i] * inv;
    __syncthreads();

    #pragma unroll
    for (int r = 0; r < 8; r++) {
        int idx = t + r*256;
        int c  = idx >> 6;
        int vl = idx & 63;
        aout[((size_t)b*CIN + n*HDIM + c)*SVOX + s0 + vl] = ot[vl*33 + c];
    }
}

extern "C" void kernel_launch(void* const* d_in, const int* in_sizes, int n_in,
                              void* d_out, int out_size, void* d_ws, size_t ws_size,
                              hipStream_t stream) {
    const float* x      = (const float*)d_in[0];
    const float* qkv_w  = (const float*)d_in[1];
    const float* qkv_b  = (const float*)d_in[2];
    const float* proj_w = (const float*)d_in[3];
    const float* proj_b = (const float*)d_in[4];
    const float* pos    = (const float*)d_in[5];
    float* out = (float*)d_out;

    const size_t HSZ = (size_t)2 * NHEAD * SVOX * HDIM;   // elems per tensor
    ushort* qb  = (ushort*)d_ws;                          // [2][4][S][32] bf16
    ushort* kbp = qb + HSZ;                               // [2][4][S][32] bf16
    float*  vfp = (float*)(kbp + HSZ);                    // [2][4][S][32] f32
    float*  attn_o = vfp + HSZ;                           // [2][128][S] f32

    gemm_mfma<0><<<dim3(SVOX/64, 384/64, 2), 256, 0, stream>>>(x, qkv_w, qkv_b, nullptr, qb, kbp, vfp);
    attn_kernel<<<dim3(SVOX/64, NHEAD, 2), 256, 0, stream>>>(qb, kbp, vfp, pos, attn_o);
    gemm_mfma<1><<<dim3(SVOX/64, CIN/64, 2), 256, 0, stream>>>(attn_o, proj_w, proj_b, out, nullptr, nullptr, nullptr);
}

// Round 6
// 64.696 us; speedup vs baseline: 6.2821x; 1.1529x over previous
//
#include <hip/hip_runtime.h>
#include <hip/hip_bf16.h>

#define SVOX 13824   // 24*24*24
#define CIN 128
#define NHEAD 4
#define HDIM 32

// attention brick geometry
#define BD 2
#define BH 4
#define BW 8
#define WD (BD+2)
#define WH (BH+2)
#define WW (BW+2)
#define NWIN (WD*WH*WW)   // 240

typedef __attribute__((ext_vector_type(8))) short short8;
typedef __attribute__((ext_vector_type(4))) float f32x4;
typedef __attribute__((ext_vector_type(4))) unsigned int uint4v;
#if defined(__has_builtin)
#if __has_builtin(__builtin_amdgcn_fdot2_f32_bf16)
#define HAVE_DOT2BF 1
typedef __attribute__((ext_vector_type(2))) __bf16 bf16x2;
#endif
#if __has_builtin(__builtin_amdgcn_mov_dpp)
#define HAVE_DPP 1
#endif
#endif

__device__ __forceinline__ unsigned short f2bf(float x) {
    unsigned u = __float_as_uint(x);
    u += 0x7FFFu + ((u >> 16) & 1u);
    return (unsigned short)(u >> 16);
}
__device__ __forceinline__ float bf2f(unsigned short s) {
    return __uint_as_float(((unsigned)s) << 16);
}
__device__ __forceinline__ unsigned packhl(float x) {
    unsigned short h = f2bf(x);
    unsigned short l = f2bf(x - bf2f(h));
    return (unsigned)h | ((unsigned)l << 16);
}
__device__ __forceinline__ float dot2bf(unsigned a, unsigned b, float c) {
#ifdef HAVE_DOT2BF
    return __builtin_amdgcn_fdot2_f32_bf16(__builtin_bit_cast(bf16x2, a),
                                           __builtin_bit_cast(bf16x2, b), c, false);
#else
    return __uint_as_float(a << 16) * __uint_as_float(b << 16)
         + __uint_as_float(a & 0xffff0000u) * __uint_as_float(b & 0xffff0000u) + c;
#endif
}
template<int CTRL>
__device__ __forceinline__ float quad_dpp(float x) {
#ifdef HAVE_DPP
    return __int_as_float(__builtin_amdgcn_mov_dpp(__float_as_int(x), CTRL, 0xf, 0xf, true));
#else
    return __shfl_xor(x, (CTRL == 0xB1) ? 1 : 2);
#endif
}

// ---------------------------------------------------------------------------
// MFMA GEMM, bf16x3 error-compensated split (error ~2^-16, effectively f32).
// MODE 0: epilogue packs q/k/v to bf16, [B][4][S][32] each
// MODE 1: epilogue writes [B][128][S] f32 directly
// ---------------------------------------------------------------------------
template<int MODE>
__global__ __launch_bounds__(256) void gemm_mfma(
    const float* __restrict__ X,
    const float* __restrict__ W,
    const float* __restrict__ bias,
    float* __restrict__ out,
    ushort* __restrict__ q_out,
    ushort* __restrict__ k_out,
    ushort* __restrict__ v_out)
{
    __shared__ __align__(16) unsigned char smem[52224];
    short*    Wh = (short*)smem;                 // [64][136] bf16 hi
    short*    Wl = (short*)(smem + 17408);       // [64][136] bf16 lo
    unsigned* Xs = (unsigned*)(smem + 34816);    // [64 s][68 k] packed hi|lo<<16
    float*    T  = (float*)smem;                 // epilogue transpose (alias)

    const int t    = threadIdx.x;
    const int s0   = blockIdx.x * 64;
    const int o0   = blockIdx.y * 64;
    const int b    = blockIdx.z;
    const int lane = t & 63;
    const int wid  = t >> 6;
    const int l15  = lane & 15;
    const int g4   = lane >> 4;          // 0..3
    const int wm   = (wid >> 1) * 32;
    const int wn   = (wid & 1) * 32;

    #pragma unroll
    for (int i = 0; i < 8; i++) {
        int f = t + i * 256;
        int row = f >> 5, c4 = f & 31;
        float4 w = *(const float4*)(W + (size_t)(o0 + row) * CIN + c4 * 4);
        unsigned short h0 = f2bf(w.x), h1 = f2bf(w.y), h2 = f2bf(w.z), h3 = f2bf(w.w);
        unsigned short l0 = f2bf(w.x - bf2f(h0)), l1 = f2bf(w.y - bf2f(h1));
        unsigned short l2 = f2bf(w.z - bf2f(h2)), l3 = f2bf(w.w - bf2f(h3));
        uint2 ph; ph.x = (unsigned)h0 | ((unsigned)h1 << 16); ph.y = (unsigned)h2 | ((unsigned)h3 << 16);
        uint2 pl; pl.x = (unsigned)l0 | ((unsigned)l1 << 16); pl.y = (unsigned)l2 | ((unsigned)l3 << 16);
        *(uint2*)(Wh + row * 136 + c4 * 4) = ph;
        *(uint2*)(Wl + row * 136 + c4 * 4) = pl;
    }

    f32x4 acc[2][2];
    #pragma unroll
    for (int mf = 0; mf < 2; mf++)
        #pragma unroll
        for (int nf = 0; nf < 2; nf++)
            acc[mf][nf] = (f32x4){0.f, 0.f, 0.f, 0.f};

    const int sx = t & 63;
    const int kg = t >> 6;

    for (int chunk = 0; chunk < 2; chunk++) {
        __syncthreads();
        unsigned pk[16];
        #pragma unroll
        for (int i = 0; i < 16; i++) {
            int k = kg * 16 + i;
            float x = X[((size_t)b * CIN + chunk * 64 + k) * SVOX + s0 + sx];
            pk[i] = packhl(x);
        }
        #pragma unroll
        for (int j = 0; j < 4; j++) {
            uint4v v;
            v.x = pk[4 * j + 0]; v.y = pk[4 * j + 1];
            v.z = pk[4 * j + 2]; v.w = pk[4 * j + 3];
            *(uint4v*)(Xs + sx * 68 + kg * 16 + 4 * j) = v;
        }
        __syncthreads();

        short8 Ah[2][2], Al[2][2];
        #pragma unroll
        for (int ks = 0; ks < 2; ks++)
            #pragma unroll
            for (int mf = 0; mf < 2; mf++) {
                int off = (wm + mf * 16 + l15) * 136 + chunk * 64 + ks * 32 + g4 * 8;
                Ah[ks][mf] = *(const short8*)(Wh + off);
                Al[ks][mf] = *(const short8*)(Wl + off);
            }

        #pragma unroll
        for (int ks = 0; ks < 2; ks++) {
            short8 Bh[2], Bl[2];
            #pragma unroll
            for (int nf = 0; nf < 2; nf++) {
                const uint4v* p = (const uint4v*)(Xs + (wn + nf * 16 + l15) * 68 + ks * 32 + g4 * 8);
                uint4v r0 = p[0], r1 = p[1];
                uint4v hv, lv;
                hv.x = __builtin_amdgcn_perm(r0.y, r0.x, 0x05040100u);
                hv.y = __builtin_amdgcn_perm(r0.w, r0.z, 0x05040100u);
                hv.z = __builtin_amdgcn_perm(r1.y, r1.x, 0x05040100u);
                hv.w = __builtin_amdgcn_perm(r1.w, r1.z, 0x05040100u);
                lv.x = __builtin_amdgcn_perm(r0.y, r0.x, 0x07060302u);
                lv.y = __builtin_amdgcn_perm(r0.w, r0.z, 0x07060302u);
                lv.z = __builtin_amdgcn_perm(r1.y, r1.x, 0x07060302u);
                lv.w = __builtin_amdgcn_perm(r1.w, r1.z, 0x07060302u);
                Bh[nf] = __builtin_bit_cast(short8, hv);
                Bl[nf] = __builtin_bit_cast(short8, lv);
            }
            #pragma unroll
            for (int mf = 0; mf < 2; mf++)
                #pragma unroll
                for (int nf = 0; nf < 2; nf++) {
                    acc[mf][nf] = __builtin_amdgcn_mfma_f32_16x16x32_bf16(Ah[ks][mf], Bh[nf], acc[mf][nf], 0, 0, 0);
                    acc[mf][nf] = __builtin_amdgcn_mfma_f32_16x16x32_bf16(Ah[ks][mf], Bl[nf], acc[mf][nf], 0, 0, 0);
                    acc[mf][nf] = __builtin_amdgcn_mfma_f32_16x16x32_bf16(Al[ks][mf], Bh[nf], acc[mf][nf], 0, 0, 0);
                }
        }
    }

    __syncthreads();

    if (MODE == 0) {
        #pragma unroll
        for (int mf = 0; mf < 2; mf++)
            #pragma unroll
            for (int nf = 0; nf < 2; nf++) {
                int s  = wn + nf * 16 + l15;
                int mb = wm + mf * 16 + g4 * 4;
                *(f32x4*)(T + s * 68 + mb) = acc[mf][nf];
            }
        __syncthreads();
        #pragma unroll
        for (int i = 0; i < 4; i++) {
            int f = t + i * 256;
            int og = f & 15, sl = f >> 4;
            float4 v = *(float4*)(T + sl * 68 + og * 4);
            int o_g = o0 + og * 4;
            v.x += bias[o_g]; v.y += bias[o_g + 1]; v.z += bias[o_g + 2]; v.w += bias[o_g + 3];
            int part = o_g >> 7, pc = o_g & 127;
            int head = pc >> 5, ic = pc & 31;
            size_t base = (((size_t)b * NHEAD + head) * SVOX + s0 + sl) * HDIM + ic;
            ushort4 u;
            u.x = f2bf(v.x); u.y = f2bf(v.y); u.z = f2bf(v.z); u.w = f2bf(v.w);
            ushort* dst = (part == 0) ? q_out : (part == 1) ? k_out : v_out;
            *(ushort4*)(dst + base) = u;
        }
    } else {
        #pragma unroll
        for (int mf = 0; mf < 2; mf++)
            #pragma unroll
            for (int nf = 0; nf < 2; nf++) {
                int s  = wn + nf * 16 + l15;
                int mb = wm + mf * 16 + g4 * 4;
                #pragma unroll
                for (int r = 0; r < 4; r++)
                    T[(mb + r) * 72 + s] = acc[mf][nf][r];
            }
        __syncthreads();
        #pragma unroll
        for (int i = 0; i < 4; i++) {
            int f = t + i * 256;
            int s4 = f & 15, m = f >> 4;
            float4 v = *(float4*)(T + m * 72 + s4 * 4);
            float bi = bias[o0 + m];
            v.x += bi; v.y += bi; v.z += bi; v.w += bi;
            *(float4*)(out + ((size_t)b * CIN + o0 + m) * SVOX + s0 + s4 * 4) = v;
        }
    }
}

// ---------------------------------------------------------------------------
// Brick-LDS windowed attention. Block = (2x4x8 voxel brick, head), 256 thr,
// 4 lanes/voxel. K,V window (4x6x10=240 vox) staged in LDS as bf16 with
// OOB zero-fill (zero K/V == exact masked semantics). All window reads are
// ds_read_b128 with compile-time offsets. Quad reduce via DPP.
// ---------------------------------------------------------------------------
__global__ __launch_bounds__(256, 4) void attn_kernel(
    const ushort* __restrict__ qbf,
    const ushort* __restrict__ kbf,
    const ushort* __restrict__ vbf,
    const float* __restrict__ pos,
    float* __restrict__ aout)
{
    __shared__ __align__(16) ushort Kl[NWIN * 32];       // 15360 B
    __shared__ __align__(16) ushort Vl[NWIN * 32];       // 15360 B
    __shared__ __align__(16) unsigned pe_p[27 * 16];     // 1728 B
    float* ot = (float*)Kl;                              // [64][36] alias, 9216 B

    const int t = threadIdx.x;
    const int br = blockIdx.x;           // 216 bricks: 12(d) x 6(h) x 3(w)
    const int n  = blockIdx.y;
    const int b  = blockIdx.z;
    const int bw_ = br % 3;
    const int bh_ = (br / 3) % 6;
    const int bd_ = br / 18;
    const int d0 = bd_ * BD, h0 = bh_ * BH, w0 = bw_ * BW;

    const ushort* kb = kbf + ((size_t)b * NHEAD + n) * (size_t)SVOX * HDIM;
    const ushort* vb = vbf + ((size_t)b * NHEAD + n) * (size_t)SVOX * HDIM;

    // stage pos (packed bf16 pairs) and the K/V window
    for (int i = t; i < 27 * 16; i += 256) {
        int w = i >> 4, cp = i & 15;
        unsigned lo = f2bf(pos[(2 * cp) * 27 + w]);
        unsigned hi = f2bf(pos[(2 * cp + 1) * 27 + w]);
        pe_p[i] = lo | (hi << 16);
    }
    #pragma unroll
    for (int i = 0; i < 4; i++) {
        int f = t + i * 256;
        if (f < NWIN * 4) {
            int u = f >> 2, ch = f & 3;
            int ud = u / (WH * WW);
            int r  = u - ud * (WH * WW);
            int uh = r / WW;
            int uw = r - uh * WW;
            int gd = d0 + ud - 1, gh = h0 + uh - 1, gw = w0 + uw - 1;
            bool valid = ((unsigned)gd < 24u) & ((unsigned)gh < 24u) & ((unsigned)gw < 24u);
            size_t gsv = valid ? (size_t)(gd * 576 + gh * 24 + gw) : 0;
            uint4 kv = *(const uint4*)(kb + gsv * HDIM + ch * 8);
            uint4 vv = *(const uint4*)(vb + gsv * HDIM + ch * 8);
            if (!valid) { kv = make_uint4(0,0,0,0); vv = make_uint4(0,0,0,0); }
            *(uint4*)(Kl + u * 32 + ch * 8) = kv;
            *(uint4*)(Vl + u * 32 + ch * 8) = vv;
        }
    }

    const int p   = t >> 2;          // local voxel 0..63
    const int sub = t & 3;           // 8-channel group
    const int pw = p & 7, ph = (p >> 3) & 3, pd = p >> 5;
    const int sv = (d0 + pd) * 576 + (h0 + ph) * 24 + w0 + pw;
    uint4 qpk = *(const uint4*)(qbf + (((size_t)b * NHEAD + n) * SVOX + sv) * HDIM + sub * 8);

    __syncthreads();

    const int wc = (pd + 1) * (WH * WW) + (ph + 1) * WW + (pw + 1);
    const ushort* Kbase = Kl + wc * 32 + sub * 8;

    float sc[27];
    #pragma unroll
    for (int s = 0; s < 27; s++) {
        const int di = s / 9 - 1, dj = (s / 3) % 3 - 1, dl = s % 3 - 1;
        const int off = (di * (WH * WW) + dj * WW + dl) * 32;
        uint4 kk = *(const uint4*)(Kbase + off);
        uint4 pp = *(const uint4*)&pe_p[s * 16 + sub * 4];
        float a = dot2bf(qpk.x, kk.x, 0.f);
        a = dot2bf(qpk.y, kk.y, a);
        a = dot2bf(qpk.z, kk.z, a);
        a = dot2bf(qpk.w, kk.w, a);
        a = dot2bf(qpk.x, pp.x, a);
        a = dot2bf(qpk.y, pp.y, a);
        a = dot2bf(qpk.z, pp.z, a);
        a = dot2bf(qpk.w, pp.w, a);
        sc[s] = a;
    }

    // quad reduce (VALU DPP, off the LDS pipe)
    #pragma unroll
    for (int s = 0; s < 27; s++) {
        sc[s] += quad_dpp<0xB1>(sc[s]);   // xor 1
        sc[s] += quad_dpp<0x4E>(sc[s]);   // xor 2
    }

    __syncthreads();   // all K reads done (Kl will be reused as ot)

    const float scale = 0.17677669529663687f;
    float mx = -1e30f;
    #pragma unroll
    for (int s = 0; s < 27; s++) {
        sc[s] *= scale;
        mx = fmaxf(mx, sc[s]);
    }
    float sum = 0.f;
    #pragma unroll
    for (int s = 0; s < 27; s++) {
        float e = __expf(sc[s] - mx);
        sc[s] = e;
        sum += e;
    }
    float inv = 1.f / sum;

    // PV from LDS (bf16 V, unpack + fma)
    const ushort* Vbase = Vl + wc * 32 + sub * 8;
    float o[8];
    #pragma unroll
    for (int i = 0; i < 8; i++) o[i] = 0.f;
    #pragma unroll
    for (int s = 0; s < 27; s++) {
        const int di = s / 9 - 1, dj = (s / 3) % 3 - 1, dl = s % 3 - 1;
        const int off = (di * (WH * WW) + dj * WW + dl) * 32;
        uint4 vv = *(const uint4*)(Vbase + off);
        float pr = sc[s];
        o[0] += pr * __uint_as_float(vv.x << 16);
        o[1] += pr * __uint_as_float(vv.x & 0xffff0000u);
        o[2] += pr * __uint_as_float(vv.y << 16);
        o[3] += pr * __uint_as_float(vv.y & 0xffff0000u);
        o[4] += pr * __uint_as_float(vv.z << 16);
        o[5] += pr * __uint_as_float(vv.z & 0xffff0000u);
        o[6] += pr * __uint_as_float(vv.w << 16);
        o[7] += pr * __uint_as_float(vv.w & 0xffff0000u);
    }

    // transpose via ot (aliases Kl; disjoint from Vl, safe post-barrier)
    #pragma unroll
    for (int i = 0; i < 8; i += 4) {
        f32x4 v4 = {o[i] * inv, o[i+1] * inv, o[i+2] * inv, o[i+3] * inv};
        *(f32x4*)(ot + p * 36 + sub * 8 + i) = v4;
    }
    __syncthreads();

    const int c = t & 31, g = t >> 5;
    const int spd = g >> 2, sph = g & 3;
    float4 va, vb4;
    va.x = ot[(spd * 32 + sph * 8 + 0) * 36 + c];
    va.y = ot[(spd * 32 + sph * 8 + 1) * 36 + c];
    va.z = ot[(spd * 32 + sph * 8 + 2) * 36 + c];
    va.w = ot[(spd * 32 + sph * 8 + 3) * 36 + c];
    vb4.x = ot[(spd * 32 + sph * 8 + 4) * 36 + c];
    vb4.y = ot[(spd * 32 + sph * 8 + 5) * 36 + c];
    vb4.z = ot[(spd * 32 + sph * 8 + 6) * 36 + c];
    vb4.w = ot[(spd * 32 + sph * 8 + 7) * 36 + c];
    size_t obase = ((size_t)b * CIN + n * HDIM + c) * SVOX
                 + (size_t)(d0 + spd) * 576 + (size_t)(h0 + sph) * 24 + w0;
    *(float4*)(aout + obase) = va;
    *(float4*)(aout + obase + 4) = vb4;
}

extern "C" void kernel_launch(void* const* d_in, const int* in_sizes, int n_in,
                              void* d_out, int out_size, void* d_ws, size_t ws_size,
                              hipStream_t stream) {
    const float* x      = (const float*)d_in[0];
    const float* qkv_w  = (const float*)d_in[1];
    const float* qkv_b  = (const float*)d_in[2];
    const float* proj_w = (const float*)d_in[3];
    const float* proj_b = (const float*)d_in[4];
    const float* pos    = (const float*)d_in[5];
    float* out = (float*)d_out;

    const size_t HSZ = (size_t)2 * NHEAD * SVOX * HDIM;   // elems per tensor
    ushort* qb  = (ushort*)d_ws;                          // bf16 [2][4][S][32]
    ushort* kbp = qb + HSZ;
    ushort* vbp = kbp + HSZ;
    float*  attn_o = (float*)(vbp + HSZ);                 // f32 [2][128][S]

    gemm_mfma<0><<<dim3(SVOX/64, 384/64, 2), 256, 0, stream>>>(x, qkv_w, qkv_b, nullptr, qb, kbp, vbp);
    attn_kernel<<<dim3(216, NHEAD, 2), 256, 0, stream>>>(qb, kbp, vbp, pos, attn_o);
    gemm_mfma<1><<<dim3(SVOX/64, CIN/64, 2), 256, 0, stream>>>(attn_o, proj_w, proj_b, out, nullptr, nullptr, nullptr);
}

// Round 7
// 46.528 us; speedup vs baseline: 8.7352x; 1.3905x over previous
//
#include <hip/hip_runtime.h>
#include <hip/hip_bf16.h>

#define SVOX 13824   // 24*24*24
#define CIN 128
#define NHEAD 4
#define HDIM 32

// attention brick geometry
#define BD 2
#define BH 4
#define BW 8
#define WD (BD+2)
#define WH (BH+2)
#define WW (BW+2)
#define NWIN (WD*WH*WW)   // 240

typedef __attribute__((ext_vector_type(8))) short short8;
typedef __attribute__((ext_vector_type(4))) float f32x4;
#if defined(__has_builtin)
#if __has_builtin(__builtin_amdgcn_fdot2_f32_bf16)
#define HAVE_DOT2BF 1
typedef __attribute__((ext_vector_type(2))) __bf16 bf16x2;
#endif
#if __has_builtin(__builtin_amdgcn_mov_dpp)
#define HAVE_DPP 1
#endif
#endif

__device__ __forceinline__ unsigned short f2bf(float x) {
    unsigned u = __float_as_uint(x);
    u += 0x7FFFu + ((u >> 16) & 1u);
    return (unsigned short)(u >> 16);
}
__device__ __forceinline__ float dot2bf(unsigned a, unsigned b, float c) {
#ifdef HAVE_DOT2BF
    return __builtin_amdgcn_fdot2_f32_bf16(__builtin_bit_cast(bf16x2, a),
                                           __builtin_bit_cast(bf16x2, b), c, false);
#else
    return __uint_as_float(a << 16) * __uint_as_float(b << 16)
         + __uint_as_float(a & 0xffff0000u) * __uint_as_float(b & 0xffff0000u) + c;
#endif
}
template<int CTRL>
__device__ __forceinline__ float quad_dpp(float x) {
#ifdef HAVE_DPP
    return __int_as_float(__builtin_amdgcn_mov_dpp(__float_as_int(x), CTRL, 0xf, 0xf, true));
#else
    return __shfl_xor(x, (CTRL == 0xB1) ? 1 : 2);
#endif
}

// ---------------------------------------------------------------------------
// Kernel 1: QKV GEMM, pure bf16 MFMA (inputs rounded once to bf16).
//   X [B][128][S] f32, W [384][128] f32 -> q/k/v bf16 [B][4][S][32]
// Tile 64(o) x 64(s), K=128 in 2 chunks. 4 waves, 32x32 each. 1 MFMA/product.
// LDS strides: W 136 ush (272B), X 72 ush (144B) -- both ==16 mod 128 B,
// so b128 fragment reads are bank-conflict-free.
// ---------------------------------------------------------------------------
__global__ __launch_bounds__(256) void qkv_gemm(
    const float* __restrict__ X,
    const float* __restrict__ W,
    const float* __restrict__ bias,
    ushort* __restrict__ q_out,
    ushort* __restrict__ k_out,
    ushort* __restrict__ v_out)
{
    __shared__ __align__(16) unsigned char smem[26624];
    ushort* Wb = (ushort*)smem;                 // [64][136] bf16
    ushort* Xs = (ushort*)(smem + 17408);       // [64 s][72 k] bf16
    float*  T  = (float*)smem;                  // epilogue alias [64][68]

    const int t    = threadIdx.x;
    const int s0   = blockIdx.x * 64;
    const int o0   = blockIdx.y * 64;
    const int b    = blockIdx.z;
    const int lane = t & 63;
    const int wid  = t >> 6;
    const int l15  = lane & 15;
    const int g4   = lane >> 4;
    const int wm   = (wid >> 1) * 32;
    const int wn   = (wid & 1) * 32;

    // stage W [64][128] as bf16
    #pragma unroll
    for (int i = 0; i < 8; i++) {
        int f = t + i * 256;
        int row = f >> 5, c4 = f & 31;
        float4 w = *(const float4*)(W + (size_t)(o0 + row) * CIN + c4 * 4);
        ushort4 u;
        u.x = f2bf(w.x); u.y = f2bf(w.y); u.z = f2bf(w.z); u.w = f2bf(w.w);
        *(ushort4*)(Wb + row * 136 + c4 * 4) = u;
    }

    f32x4 acc[2][2];
    #pragma unroll
    for (int mf = 0; mf < 2; mf++)
        #pragma unroll
        for (int nf = 0; nf < 2; nf++)
            acc[mf][nf] = (f32x4){0.f, 0.f, 0.f, 0.f};

    const int sx = t & 63;
    const int kg = t >> 6;

    for (int chunk = 0; chunk < 2; chunk++) {
        __syncthreads();
        // stage X chunk [k=64][s=64] -> Xs[s][k] bf16 (coalesced dword loads)
        ushort xk[16];
        #pragma unroll
        for (int i = 0; i < 16; i++) {
            int k = kg * 16 + i;
            xk[i] = f2bf(X[((size_t)b * CIN + chunk * 64 + k) * SVOX + s0 + sx]);
        }
        #pragma unroll
        for (int j = 0; j < 2; j++) {
            short8 v;
            #pragma unroll
            for (int e = 0; e < 8; e++) v[e] = (short)xk[j * 8 + e];
            *(short8*)(Xs + sx * 72 + kg * 16 + j * 8) = v;
        }
        __syncthreads();

        #pragma unroll
        for (int ks = 0; ks < 2; ks++) {
            short8 Af[2], Bf[2];
            #pragma unroll
            for (int mf = 0; mf < 2; mf++)
                Af[mf] = *(const short8*)(Wb + (wm + mf * 16 + l15) * 136 + chunk * 64 + ks * 32 + g4 * 8);
            #pragma unroll
            for (int nf = 0; nf < 2; nf++)
                Bf[nf] = *(const short8*)(Xs + (wn + nf * 16 + l15) * 72 + ks * 32 + g4 * 8);
            #pragma unroll
            for (int mf = 0; mf < 2; mf++)
                #pragma unroll
                for (int nf = 0; nf < 2; nf++)
                    acc[mf][nf] = __builtin_amdgcn_mfma_f32_16x16x32_bf16(Af[mf], Bf[nf], acc[mf][nf], 0, 0, 0);
        }
    }

    __syncthreads();
    // epilogue: transpose via LDS, pack bf16, scatter to q/k/v [B][4][S][32]
    #pragma unroll
    for (int mf = 0; mf < 2; mf++)
        #pragma unroll
        for (int nf = 0; nf < 2; nf++) {
            int s  = wn + nf * 16 + l15;
            int mb = wm + mf * 16 + g4 * 4;
            *(f32x4*)(T + s * 68 + mb) = acc[mf][nf];
        }
    __syncthreads();
    #pragma unroll
    for (int i = 0; i < 4; i++) {
        int f = t + i * 256;
        int og = f & 15, sl = f >> 4;
        float4 v = *(float4*)(T + sl * 68 + og * 4);
        int o_g = o0 + og * 4;
        v.x += bias[o_g]; v.y += bias[o_g + 1]; v.z += bias[o_g + 2]; v.w += bias[o_g + 3];
        int part = o_g >> 7, pc = o_g & 127;
        int head = pc >> 5, ic = pc & 31;
        size_t base = (((size_t)b * NHEAD + head) * SVOX + s0 + sl) * HDIM + ic;
        ushort4 u;
        u.x = f2bf(v.x); u.y = f2bf(v.y); u.z = f2bf(v.z); u.w = f2bf(v.w);
        ushort* dst = (part == 0) ? q_out : (part == 1) ? k_out : v_out;
        *(ushort4*)(dst + base) = u;
    }
}

// ---------------------------------------------------------------------------
// Kernel 2: brick-LDS windowed attention (as R6) but writes bf16 [B][S][128]
// voxel-major directly (no LDS output transpose, single barrier).
// ---------------------------------------------------------------------------
__global__ __launch_bounds__(256, 4) void attn_kernel(
    const ushort* __restrict__ qbf,
    const ushort* __restrict__ kbf,
    const ushort* __restrict__ vbf,
    const float* __restrict__ pos,
    ushort* __restrict__ aout)
{
    __shared__ __align__(16) ushort Kl[NWIN * 32];       // 15360 B
    __shared__ __align__(16) ushort Vl[NWIN * 32];       // 15360 B
    __shared__ __align__(16) unsigned pe_p[27 * 16];     // 1728 B

    const int t = threadIdx.x;
    const int br = blockIdx.x;           // 216 bricks: 12(d) x 6(h) x 3(w)
    const int n  = blockIdx.y;
    const int b  = blockIdx.z;
    const int bw_ = br % 3;
    const int bh_ = (br / 3) % 6;
    const int bd_ = br / 18;
    const int d0 = bd_ * BD, h0 = bh_ * BH, w0 = bw_ * BW;

    const ushort* kb = kbf + ((size_t)b * NHEAD + n) * (size_t)SVOX * HDIM;
    const ushort* vb = vbf + ((size_t)b * NHEAD + n) * (size_t)SVOX * HDIM;

    for (int i = t; i < 27 * 16; i += 256) {
        int w = i >> 4, cp = i & 15;
        unsigned lo = f2bf(pos[(2 * cp) * 27 + w]);
        unsigned hi = f2bf(pos[(2 * cp + 1) * 27 + w]);
        pe_p[i] = lo | (hi << 16);
    }
    #pragma unroll
    for (int i = 0; i < 4; i++) {
        int f = t + i * 256;
        if (f < NWIN * 4) {
            int u = f >> 2, ch = f & 3;
            int ud = u / (WH * WW);
            int r  = u - ud * (WH * WW);
            int uh = r / WW;
            int uw = r - uh * WW;
            int gd = d0 + ud - 1, gh = h0 + uh - 1, gw = w0 + uw - 1;
            bool valid = ((unsigned)gd < 24u) & ((unsigned)gh < 24u) & ((unsigned)gw < 24u);
            size_t gsv = valid ? (size_t)(gd * 576 + gh * 24 + gw) : 0;
            uint4 kv = *(const uint4*)(kb + gsv * HDIM + ch * 8);
            uint4 vv = *(const uint4*)(vb + gsv * HDIM + ch * 8);
            if (!valid) { kv = make_uint4(0,0,0,0); vv = make_uint4(0,0,0,0); }
            *(uint4*)(Kl + u * 32 + ch * 8) = kv;
            *(uint4*)(Vl + u * 32 + ch * 8) = vv;
        }
    }

    const int p   = t >> 2;          // local voxel 0..63
    const int sub = t & 3;           // 8-channel group
    const int pw = p & 7, ph = (p >> 3) & 3, pd = p >> 5;
    const int sv = (d0 + pd) * 576 + (h0 + ph) * 24 + w0 + pw;
    uint4 qpk = *(const uint4*)(qbf + (((size_t)b * NHEAD + n) * SVOX + sv) * HDIM + sub * 8);

    __syncthreads();

    const int wc = (pd + 1) * (WH * WW) + (ph + 1) * WW + (pw + 1);
    const ushort* Kbase = Kl + wc * 32 + sub * 8;

    float sc[27];
    #pragma unroll
    for (int s = 0; s < 27; s++) {
        const int di = s / 9 - 1, dj = (s / 3) % 3 - 1, dl = s % 3 - 1;
        const int off = (di * (WH * WW) + dj * WW + dl) * 32;
        uint4 kk = *(const uint4*)(Kbase + off);
        uint4 pp = *(const uint4*)&pe_p[s * 16 + sub * 4];
        float a = dot2bf(qpk.x, kk.x, 0.f);
        a = dot2bf(qpk.y, kk.y, a);
        a = dot2bf(qpk.z, kk.z, a);
        a = dot2bf(qpk.w, kk.w, a);
        a = dot2bf(qpk.x, pp.x, a);
        a = dot2bf(qpk.y, pp.y, a);
        a = dot2bf(qpk.z, pp.z, a);
        a = dot2bf(qpk.w, pp.w, a);
        sc[s] = a;
    }

    #pragma unroll
    for (int s = 0; s < 27; s++) {
        sc[s] += quad_dpp<0xB1>(sc[s]);   // xor 1
        sc[s] += quad_dpp<0x4E>(sc[s]);   // xor 2
    }

    const float scale = 0.17677669529663687f;
    float mx = -1e30f;
    #pragma unroll
    for (int s = 0; s < 27; s++) {
        sc[s] *= scale;
        mx = fmaxf(mx, sc[s]);
    }
    float sum = 0.f;
    #pragma unroll
    for (int s = 0; s < 27; s++) {
        float e = __expf(sc[s] - mx);
        sc[s] = e;
        sum += e;
    }
    float inv = 1.f / sum;

    const ushort* Vbase = Vl + wc * 32 + sub * 8;
    float o[8];
    #pragma unroll
    for (int i = 0; i < 8; i++) o[i] = 0.f;
    #pragma unroll
    for (int s = 0; s < 27; s++) {
        const int di = s / 9 - 1, dj = (s / 3) % 3 - 1, dl = s % 3 - 1;
        const int off = (di * (WH * WW) + dj * WW + dl) * 32;
        uint4 vv = *(const uint4*)(Vbase + off);
        float pr = sc[s];
        o[0] += pr * __uint_as_float(vv.x << 16);
        o[1] += pr * __uint_as_float(vv.x & 0xffff0000u);
        o[2] += pr * __uint_as_float(vv.y << 16);
        o[3] += pr * __uint_as_float(vv.y & 0xffff0000u);
        o[4] += pr * __uint_as_float(vv.z << 16);
        o[5] += pr * __uint_as_float(vv.z & 0xffff0000u);
        o[6] += pr * __uint_as_float(vv.w << 16);
        o[7] += pr * __uint_as_float(vv.w & 0xffff0000u);
    }

    // direct bf16 store, voxel-major [b][s][128], c = n*32 + sub*8 + i
    uint4 ou;
    ou.x = (unsigned)f2bf(o[0] * inv) | ((unsigned)f2bf(o[1] * inv) << 16);
    ou.y = (unsigned)f2bf(o[2] * inv) | ((unsigned)f2bf(o[3] * inv) << 16);
    ou.z = (unsigned)f2bf(o[4] * inv) | ((unsigned)f2bf(o[5] * inv) << 16);
    ou.w = (unsigned)f2bf(o[6] * inv) | ((unsigned)f2bf(o[7] * inv) << 16);
    *(uint4*)(aout + ((size_t)b * SVOX + sv) * CIN + n * HDIM + sub * 8) = ou;
}

// ---------------------------------------------------------------------------
// Kernel 3: proj GEMM, pure bf16 MFMA. X = attn_o bf16 [B][S][128] voxel-major
// (== MFMA B-frag layout, staged by straight copy). out [B][128][S] f32.
// ---------------------------------------------------------------------------
__global__ __launch_bounds__(256) void proj_gemm(
    const ushort* __restrict__ Xa,
    const float* __restrict__ W,
    const float* __restrict__ bias,
    float* __restrict__ out)
{
    __shared__ __align__(16) unsigned char smem[34816];
    ushort* Wb = (ushort*)smem;                 // [64][136] bf16
    ushort* Xs = (ushort*)(smem + 17408);       // [64 s][136 k] bf16
    float*  T  = (float*)smem;                  // epilogue alias [64][72]

    const int t    = threadIdx.x;
    const int s0   = blockIdx.x * 64;
    const int o0   = blockIdx.y * 64;
    const int b    = blockIdx.z;
    const int lane = t & 63;
    const int wid  = t >> 6;
    const int l15  = lane & 15;
    const int g4   = lane >> 4;
    const int wm   = (wid >> 1) * 32;
    const int wn   = (wid & 1) * 32;

    // stage W [64][128] bf16
    #pragma unroll
    for (int i = 0; i < 8; i++) {
        int f = t + i * 256;
        int row = f >> 5, c4 = f & 31;
        float4 w = *(const float4*)(W + (size_t)(o0 + row) * CIN + c4 * 4);
        ushort4 u;
        u.x = f2bf(w.x); u.y = f2bf(w.y); u.z = f2bf(w.z); u.w = f2bf(w.w);
        *(ushort4*)(Wb + row * 136 + c4 * 4) = u;
    }
    // stage X [64 s][128 c] bf16 - straight vectorized copy
    #pragma unroll
    for (int i = 0; i < 4; i++) {
        int f = t + i * 256;
        int row = f >> 4, c8 = f & 15;
        *(uint4*)(Xs + row * 136 + c8 * 8) =
            *(const uint4*)(Xa + ((size_t)b * SVOX + s0 + row) * CIN + c8 * 8);
    }
    __syncthreads();

    f32x4 acc[2][2];
    #pragma unroll
    for (int mf = 0; mf < 2; mf++)
        #pragma unroll
        for (int nf = 0; nf < 2; nf++)
            acc[mf][nf] = (f32x4){0.f, 0.f, 0.f, 0.f};

    #pragma unroll
    for (int ks = 0; ks < 4; ks++) {
        short8 Af[2], Bf[2];
        #pragma unroll
        for (int mf = 0; mf < 2; mf++)
            Af[mf] = *(const short8*)(Wb + (wm + mf * 16 + l15) * 136 + ks * 32 + g4 * 8);
        #pragma unroll
        for (int nf = 0; nf < 2; nf++)
            Bf[nf] = *(const short8*)(Xs + (wn + nf * 16 + l15) * 136 + ks * 32 + g4 * 8);
        #pragma unroll
        for (int mf = 0; mf < 2; mf++)
            #pragma unroll
            for (int nf = 0; nf < 2; nf++)
                acc[mf][nf] = __builtin_amdgcn_mfma_f32_16x16x32_bf16(Af[mf], Bf[nf], acc[mf][nf], 0, 0, 0);
    }

    __syncthreads();
    // epilogue: [m][s] transpose -> coalesced f32 store to [B][128][S]
    #pragma unroll
    for (int mf = 0; mf < 2; mf++)
        #pragma unroll
        for (int nf = 0; nf < 2; nf++) {
            int s  = wn + nf * 16 + l15;
            int mb = wm + mf * 16 + g4 * 4;
            #pragma unroll
            for (int r = 0; r < 4; r++)
                T[(mb + r) * 72 + s] = acc[mf][nf][r];
        }
    __syncthreads();
    #pragma unroll
    for (int i = 0; i < 4; i++) {
        int f = t + i * 256;
        int s4 = f & 15, m = f >> 4;
        float4 v = *(float4*)(T + m * 72 + s4 * 4);
        float bi = bias[o0 + m];
        v.x += bi; v.y += bi; v.z += bi; v.w += bi;
        *(float4*)(out + ((size_t)b * CIN + o0 + m) * SVOX + s0 + s4 * 4) = v;
    }
}

extern "C" void kernel_launch(void* const* d_in, const int* in_sizes, int n_in,
                              void* d_out, int out_size, void* d_ws, size_t ws_size,
                              hipStream_t stream) {
    const float* x      = (const float*)d_in[0];
    const float* qkv_w  = (const float*)d_in[1];
    const float* qkv_b  = (const float*)d_in[2];
    const float* proj_w = (const float*)d_in[3];
    const float* proj_b = (const float*)d_in[4];
    const float* pos    = (const float*)d_in[5];
    float* out = (float*)d_out;

    const size_t HSZ = (size_t)2 * NHEAD * SVOX * HDIM;   // elems per q/k/v tensor
    ushort* qb  = (ushort*)d_ws;                          // bf16 [2][4][S][32]
    ushort* kbp = qb + HSZ;
    ushort* vbp = kbp + HSZ;
    ushort* attn_o = vbp + HSZ;                           // bf16 [2][S][128]

    qkv_gemm<<<dim3(SVOX/64, 384/64, 2), 256, 0, stream>>>(x, qkv_w, qkv_b, qb, kbp, vbp);
    attn_kernel<<<dim3(216, NHEAD, 2), 256, 0, stream>>>(qb, kbp, vbp, pos, attn_o);
    proj_gemm<<<dim3(SVOX/64, CIN/64, 2), 256, 0, stream>>>(attn_o, proj_w, proj_b, out);
}